// Round 3
// baseline (75292.731 us; speedup 1.0000x reference)
//
#include <hip/hip_runtime.h>
#include <stdint.h>

#define AGT __HIP_MEMORY_SCOPE_AGENT

typedef float f32x4 __attribute__((ext_vector_type(4)));
typedef short s16x8 __attribute__((ext_vector_type(8)));

__device__ __forceinline__ uint16_t f2bf(float f){
  union { float f; uint32_t u; } v; v.f = f;
  uint32_t r = v.u + 0x7FFFu + ((v.u >> 16) & 1u);
  return (uint16_t)(r >> 16);
}
__device__ __forceinline__ float bf2f(uint16_t u){
  union { uint32_t u; float f; } v; v.u = ((uint32_t)u) << 16; return v.f;
}
// split a,b into hi bf16 pair (returned) and lo residual bf16 pair (out param)
__device__ __forceinline__ uint32_t splitpack(float a, float b, uint32_t& lo){
  uint16_t ah = f2bf(a), bh = f2bf(b);
  float ar = a - bf2f(ah), br = b - bf2f(bh);
  lo = (uint32_t)f2bf(ar) | ((uint32_t)f2bf(br) << 16);
  return (uint32_t)ah | ((uint32_t)bh << 16);
}
__device__ __forceinline__ float sigf(float x){ return 1.0f / (1.0f + __expf(-x)); }

__device__ __forceinline__ f32x4 MFMA16(s16x8 a, s16x8 b, f32x4 c){
  return __builtin_amdgcn_mfma_f32_16x16x32_bf16(a, b, c, 0, 0, 0);
}

// read a 16B A-fragment from swizzled LDS: row b, k-byte-offset kbyte (multiple of 16)
__device__ __forceinline__ s16x8 ldsA(const uint32_t* AH, int b, int kbyte){
  int off = b*512 + (kbyte ^ ((b & 7) << 4));
  return *(const s16x8*)((const uint8_t*)AH + off);
}

// gather a [32][256] f32 global buffer -> split hi/lo swizzled LDS A-images
__device__ __forceinline__ void gather_split(const float* src, uint32_t* Ahi, uint32_t* Alo, int tid){
  const int p = tid & 127;            // column pair
  const int bh = (tid >> 7) * 16;     // batch half
  #pragma unroll
  for (int i = 0; i < 16; ++i){
    int b = bh + i;
    float va = __hip_atomic_load(&src[b*256 + 2*p],     __ATOMIC_RELAXED, AGT);
    float vb = __hip_atomic_load(&src[b*256 + 2*p + 1], __ATOMIC_RELAXED, AGT);
    uint32_t lo, hi = splitpack(va, vb, lo);
    int off = b*512 + ((p*4) ^ ((b & 7) << 4));
    *(uint32_t*)((uint8_t*)Ahi + off) = hi;
    *(uint32_t*)((uint8_t*)Alo + off) = lo;
  }
}

// 3-product split GEMM with register-resident B-fragments
__device__ __forceinline__ void mm3(const uint32_t* Ahi, const uint32_t* Alo,
                                    const s16x8* Bh, const s16x8* Bl,
                                    int lm, int lq, f32x4& a0, f32x4& a1){
  #pragma unroll
  for (int kt = 0; kt < 8; ++kt){
    int kb = kt*64 + lq*16;
    s16x8 h0v = ldsA(Ahi, lm, kb), h1v = ldsA(Ahi, 16 + lm, kb);
    s16x8 l0v = ldsA(Alo, lm, kb), l1v = ldsA(Alo, 16 + lm, kb);
    a0 = MFMA16(h0v, Bh[kt], a0);  a1 = MFMA16(h1v, Bh[kt], a1);
    a0 = MFMA16(h0v, Bl[kt], a0);  a1 = MFMA16(h1v, Bl[kt], a1);
    a0 = MFMA16(l0v, Bh[kt], a0);  a1 = MFMA16(l1v, Bh[kt], a1);
  }
}

// 3-product split GEMM with B-fragments loaded from global (used once per chunk)
__device__ __forceinline__ void mm3g(const uint32_t* Ahi, const uint32_t* Alo,
                                     const uint16_t* Wh, const uint16_t* Wl,
                                     int r, int lm, int lq, f32x4& a0, f32x4& a1){
  #pragma unroll
  for (int kt = 0; kt < 8; ++kt){
    size_t o = (size_t)r*256 + kt*32 + lq*8;
    s16x8 bh = *(const s16x8*)(Wh + o);
    s16x8 bl = *(const s16x8*)(Wl + o);
    int kb = kt*64 + lq*16;
    s16x8 h0v = ldsA(Ahi, lm, kb), h1v = ldsA(Ahi, 16 + lm, kb);
    s16x8 l0v = ldsA(Alo, lm, kb), l1v = ldsA(Alo, 16 + lm, kb);
    a0 = MFMA16(h0v, bh, a0);  a1 = MFMA16(h1v, bh, a1);
    a0 = MFMA16(h0v, bl, a0);  a1 = MFMA16(h1v, bl, a1);
    a0 = MFMA16(l0v, bh, a0);  a1 = MFMA16(l1v, bh, a1);
  }
}

// ---------------- prep: split weights to bf16 hi/lo, fused biases, head transposes ----------------
__global__ __launch_bounds__(256) void prep_k(
    const float* __restrict__ Wih1, const float* __restrict__ Whh1,
    const float* __restrict__ bih1, const float* __restrict__ bhh1,
    const float* __restrict__ Wih2, const float* __restrict__ Whh2,
    const float* __restrict__ bih2, const float* __restrict__ bhh2,
    const float* __restrict__ Wo1, const float* __restrict__ Wo2,
    uint16_t* __restrict__ W1ih_h, uint16_t* __restrict__ W1ih_l,
    uint16_t* __restrict__ W1hh_h, uint16_t* __restrict__ W1hh_l,
    uint16_t* __restrict__ W2ih_h, uint16_t* __restrict__ W2ih_l,
    uint16_t* __restrict__ W2hh_h, uint16_t* __restrict__ W2hh_l,
    float* __restrict__ bias1, float* __restrict__ bias2,
    float* __restrict__ Wo1T, float* __restrict__ Wo2T)
{
  int i = blockIdx.x * 256 + threadIdx.x;
  if (i < 262144){
    float w; uint16_t h;
    w = Wih1[i]; h = f2bf(w); W1ih_h[i] = h; W1ih_l[i] = f2bf(w - bf2f(h));
    w = Whh1[i]; h = f2bf(w); W1hh_h[i] = h; W1hh_l[i] = f2bf(w - bf2f(h));
    w = Wih2[i]; h = f2bf(w); W2ih_h[i] = h; W2ih_l[i] = f2bf(w - bf2f(h));
    w = Whh2[i]; h = f2bf(w); W2hh_h[i] = h; W2hh_l[i] = f2bf(w - bf2f(h));
  }
  if (i < 1024){ bias1[i] = bih1[i] + bhh1[i]; bias2[i] = bih2[i] + bhh2[i]; }
  if (i < 524288){ Wo1T[i] = Wo1[(size_t)(i & 511)*1024 + (i >> 9)]; }
  if (i < 131072){ Wo2T[i] = Wo2[(size_t)(i & 255)*512 + (i >> 8)]; }
}

// ---------------- xsplit: x -> per-t swizzled LDS-image hi/lo planes ----------------
__global__ __launch_bounds__(256, 1) void xsplit_k(
    const float* __restrict__ x, uint32_t* __restrict__ Xhi, uint32_t* __restrict__ Xlo)
{
  __shared__ uint32_t HI[4096];
  __shared__ uint32_t LO[4096];
  const int t = blockIdx.x, tid = threadIdx.x;
  const int b = tid >> 3, seg = tid & 7;
  const float4* xr = (const float4*)(x + ((size_t)b*6400 + t)*256 + seg*32);
  #pragma unroll
  for (int ii = 0; ii < 8; ++ii){
    float4 v = xr[ii];
    int p0 = seg*16 + ii*2;
    uint32_t lo0, lo1;
    uint32_t hi0 = splitpack(v.x, v.y, lo0);
    uint32_t hi1 = splitpack(v.z, v.w, lo1);
    int o0 = (b*512 + (((p0  )*4) ^ ((b&7)<<4))) >> 2;
    int o1 = (b*512 + (((p0+1)*4) ^ ((b&7)<<4))) >> 2;
    HI[o0] = hi0; LO[o0] = lo0;
    HI[o1] = hi1; LO[o1] = lo1;
  }
  __syncthreads();
  uint4* gh = (uint4*)(Xhi + (size_t)t*4096);
  uint4* gl = (uint4*)(Xlo + (size_t)t*4096);
  const uint4* sh = (const uint4*)HI;
  const uint4* sl = (const uint4*)LO;
  #pragma unroll
  for (int q = 0; q < 4; ++q){
    gh[q*256 + tid] = sh[q*256 + tid];
    gl[q*256 + tid] = sl[q*256 + tid];
  }
}

// ---------------- phase B: persistent 16-WG flag-synced scan (fp32-accurate) ----------------
// NOTE: plain launch (no hipLaunchCooperativeKernel). No grid.sync() is used;
// 16 blocks on 256 CUs are always co-resident; ordering is via release/acquire flags.
__global__ __launch_bounds__(256, 1) void scan_k(
    const float* __restrict__ h0, const float* __restrict__ c0,
    const float* __restrict__ h20, const float* __restrict__ c20,
    const float* __restrict__ Wp,
    const uint16_t* __restrict__ W1hh_h, const uint16_t* __restrict__ W1hh_l,
    const uint16_t* __restrict__ W1ih_h, const uint16_t* __restrict__ W1ih_l,
    const uint16_t* __restrict__ W2ih_h, const uint16_t* __restrict__ W2ih_l,
    const uint16_t* __restrict__ W2hh_h, const uint16_t* __restrict__ W2hh_l,
    const float* __restrict__ bias1, const float* __restrict__ bias2,
    const uint32_t* __restrict__ Xhi, const uint32_t* __restrict__ Xlo,
    float* HistRing, uint32_t* flags, uint32_t* flags2,
    float* Pbuf, float* L2buf, float* H2buf, float* HcHist, float* upx)
{
  __shared__ uint32_t A_hi_s[4096];          // [32][256] bf16-hi swizzled (16KB)
  __shared__ uint32_t A_lo_s[4096];          // lo residual (16KB)
  __shared__ float SGf[2048];                // [4 gates][32 b][16 m] f32 (8KB) + scratch
  __shared__ float PH[2560];                 // [80][32] h score partials
  __shared__ float PC[2560];                 // [80][32] c score partials

  const int j = blockIdx.x;
  const int tid = threadIdx.x;
  const int w = tid >> 6;                    // wave == gate index (i,f,g,o)
  const int l = tid & 63;
  const int lm = l & 15, lq = l >> 4;
  const int bE = tid >> 3, mp = tid & 7;
  const int m0 = 2*mp, m1 = m0 + 1;

  // resident B-fragments for W_hh1 and W_ih1 (hi+lo)
  const int r = w*256 + j*16 + lm;
  s16x8 Bhh_h[8], Bhh_l[8], Bih_h[8], Bih_l[8];
  #pragma unroll
  for (int kt = 0; kt < 8; ++kt){
    size_t o = (size_t)r*256 + kt*32 + lq*8;
    Bhh_h[kt] = *(const s16x8*)(W1hh_h + o);
    Bhh_l[kt] = *(const s16x8*)(W1hh_l + o);
    Bih_h[kt] = *(const s16x8*)(W1ih_h + o);
    Bih_l[kt] = *(const s16x8*)(W1ih_l + o);
  }
  const float b1v = bias1[r];
  const float b2v = bias2[r];
  const float wp0 = Wp[j*16 + m0];
  const float wp1 = Wp[j*16 + m1];

  float c1a = c0[bE*256 + j*16 + m0];
  float c1b = c0[bE*256 + j*16 + m1];
  float c2a = c20[bE*256 + j*16 + m0];
  float c2b = c20[bE*256 + j*16 + m1];

  // init H2buf slot 0 (own slice) and HistRing slot 0 = h0 (own slice)
  __hip_atomic_store(&H2buf[bE*256 + j*16 + m0], h20[bE*256 + j*16 + m0], __ATOMIC_RELAXED, AGT);
  __hip_atomic_store(&H2buf[bE*256 + j*16 + m1], h20[bE*256 + j*16 + m1], __ATOMIC_RELAXED, AGT);
  __hip_atomic_store(&HistRing[bE*256 + j*16 + m0], h0[bE*256 + j*16 + m0], __ATOMIC_RELAXED, AGT);
  __hip_atomic_store(&HistRing[bE*256 + j*16 + m1], h0[bE*256 + j*16 + m1], __ATOMIC_RELAXED, AGT);
  __syncthreads();
  if (tid == 0) __hip_atomic_store(&flags[j], 1u, __ATOMIC_RELEASE, AGT);

  // prologue: x-projection accumulator for step 0
  f32x4 xacc0 = {0.f,0.f,0.f,0.f}, xacc1 = {0.f,0.f,0.f,0.f};
  {
    const uint4* gh = (const uint4*)Xhi;
    const uint4* gl = (const uint4*)Xlo;
    #pragma unroll
    for (int q = 0; q < 4; ++q){
      ((uint4*)A_hi_s)[q*256 + tid] = gh[q*256 + tid];
      ((uint4*)A_lo_s)[q*256 + tid] = gl[q*256 + tid];
    }
    __syncthreads();
    mm3(A_hi_s, A_lo_s, Bih_h, Bih_l, lm, lq, xacc0, xacc1);
  }

  float* hh = HcHist + (size_t)j*81920;

  for (int it = 0; it < 6400; ++it){
    const int lch = it % 80;
    if (tid < 16){
      while (__hip_atomic_load(&flags[tid], __ATOMIC_ACQUIRE, AGT) < (uint32_t)(it + 1))
        __builtin_amdgcn_s_sleep(1);
    }
    __syncthreads();
    gather_split(HistRing + (size_t)(it & 1)*8192, A_hi_s, A_lo_s, tid);
    __syncthreads();
    // gates = x-part (carried) + h @ Whh1^T  (split, fp32-accurate)
    f32x4 acc0 = xacc0, acc1 = xacc1;
    mm3(A_hi_s, A_lo_s, Bhh_h, Bhh_l, lm, lq, acc0, acc1);
    #pragma unroll
    for (int i = 0; i < 4; ++i){
      int b0 = lq*4 + i;
      SGf[w*512 + b0*16 + lm]      = acc0[i] + b1v;
      SGf[w*512 + (b0+16)*16 + lm] = acc1[i] + b1v;
    }
    __syncthreads();
    // elementwise LSTM update + fp32 history + exchange post + pooling partials
    {
      float gi0 = SGf[bE*16+m0],      gi1 = SGf[bE*16+m1];
      float gf0 = SGf[512+bE*16+m0],  gf1 = SGf[512+bE*16+m1];
      float gg0 = SGf[1024+bE*16+m0], gg1 = SGf[1024+bE*16+m1];
      float go0 = SGf[1536+bE*16+m0], go1 = SGf[1536+bE*16+m1];
      float cn0 = sigf(gf0)*c1a + sigf(gi0)*tanhf(gg0);
      float cn1 = sigf(gf1)*c1b + sigf(gi1)*tanhf(gg1);
      float hn0 = sigf(go0)*tanhf(cn0);
      float hn1 = sigf(go1)*tanhf(cn1);
      c1a = cn0; c1b = cn1;
      int o = (lch*32 + bE)*16;
      hh[o + m0] = hn0; hh[o + m1] = hn1;
      hh[40960 + o + m0] = cn0; hh[40960 + o + m1] = cn1;
      int sl = (it + 1) & 1;
      __hip_atomic_store(&HistRing[(size_t)sl*8192 + bE*256 + j*16 + m0], hn0, __ATOMIC_RELAXED, AGT);
      __hip_atomic_store(&HistRing[(size_t)sl*8192 + bE*256 + j*16 + m1], hn1, __ATOMIC_RELAXED, AGT);
      float ph = hn0*wp0 + hn1*wp1;
      float pc = cn0*wp0 + cn1*wp1;
      ph += __shfl_xor(ph, 1); ph += __shfl_xor(ph, 2); ph += __shfl_xor(ph, 4);
      pc += __shfl_xor(pc, 1); pc += __shfl_xor(pc, 2); pc += __shfl_xor(pc, 4);
      if (mp == 0){ PH[lch*32 + bE] = ph; PC[lch*32 + bE] = pc; }
    }
    __syncthreads();
    if (tid == 0) __hip_atomic_store(&flags[j], (uint32_t)(it + 2), __ATOMIC_RELEASE, AGT);

    if (lch == 79){
      const int ci = it / 80;
      // (a) post score partials + c2 partial
      for (int x2 = tid; x2 < 2560; x2 += 256){
        __hip_atomic_store(&Pbuf[j*5152 + x2],        PH[x2], __ATOMIC_RELAXED, AGT);
        __hip_atomic_store(&Pbuf[j*5152 + 2560 + x2], PC[x2], __ATOMIC_RELAXED, AGT);
      }
      {
        float pc2 = c2a*wp0 + c2b*wp1;
        pc2 += __shfl_xor(pc2, 1); pc2 += __shfl_xor(pc2, 2); pc2 += __shfl_xor(pc2, 4);
        if (mp == 0) __hip_atomic_store(&Pbuf[j*5152 + 5120 + bE], pc2, __ATOMIC_RELAXED, AGT);
      }
      __syncthreads();
      if (tid == 0) __hip_atomic_store(&flags2[j], (uint32_t)(2*ci + 1), __ATOMIC_RELEASE, AGT);
      if (tid < 16){
        while (__hip_atomic_load(&flags2[tid], __ATOMIC_ACQUIRE, AGT) < (uint32_t)(2*ci + 1))
          __builtin_amdgcn_s_sleep(1);
      }
      __syncthreads();
      // (b) sum partials across WGs
      for (int x2 = tid; x2 < 5152; x2 += 256){
        float s = 0.f;
        #pragma unroll
        for (int k = 0; k < 16; ++k)
          s += __hip_atomic_load(&Pbuf[k*5152 + x2], __ATOMIC_RELAXED, AGT);
        if (x2 < 2560) PH[x2] = s;
        else if (x2 < 5120) PC[x2 - 2560] = s;
        else SGf[x2 - 5120] = s;            // sc2[b]
      }
      __syncthreads();
      // (c) softmax (redundant per WG)
      if (tid < 32){
        int b = tid;
        float mx = -1e30f;
        for (int l2 = 0; l2 < 80; ++l2) mx = fmaxf(mx, PH[l2*32 + b]);
        float s = 0.f;
        for (int l2 = 0; l2 < 80; ++l2){ float e = __expf(PH[l2*32+b] - mx); PH[l2*32+b] = e; s += e; }
        float inv = 1.f / s;
        for (int l2 = 0; l2 < 80; ++l2) PH[l2*32+b] *= inv;
        float mc = SGf[b];
        for (int l2 = 0; l2 < 80; ++l2) mc = fmaxf(mc, PC[l2*32 + b]);
        s = 0.f;
        for (int l2 = 0; l2 < 80; ++l2){ float e = __expf(PC[l2*32+b] - mc); PC[l2*32+b] = e; s += e; }
        float e81 = __expf(SGf[b] - mc); s += e81;
        inv = 1.f / s;
        for (int l2 = 0; l2 < 80; ++l2) PC[l2*32+b] *= inv;
        SGf[32 + b] = e81 * inv;
      }
      __syncthreads();
      // (d)+(f) pooled c2 and l2_in from fp32 private history
      float cpa = 0.f, cpb = 0.f, la = 0.f, lb = 0.f;
      for (int l2 = 0; l2 < 80; ++l2){
        float whv = PH[l2*32 + bE], wcv = PC[l2*32 + bE];
        int o = (l2*32 + bE)*16;
        la  += whv * hh[o + m0];          lb  += whv * hh[o + m1];
        cpa += wcv * hh[40960 + o + m0];  cpb += wcv * hh[40960 + o + m1];
      }
      { float w81 = SGf[32 + bE]; cpa += w81 * c2a; cpb += w81 * c2b; }
      __hip_atomic_store(&L2buf[bE*256 + j*16 + m0], la, __ATOMIC_RELAXED, AGT);
      __hip_atomic_store(&L2buf[bE*256 + j*16 + m1], lb, __ATOMIC_RELAXED, AGT);
      __syncthreads();
      if (tid == 0) __hip_atomic_store(&flags2[j], (uint32_t)(2*ci + 2), __ATOMIC_RELEASE, AGT);
      if (tid < 16){
        while (__hip_atomic_load(&flags2[tid], __ATOMIC_ACQUIRE, AGT) < (uint32_t)(2*ci + 2))
          __builtin_amdgcn_s_sleep(1);
      }
      __syncthreads();
      // (g) gates2 = l2_in@W2ih^T + h2@W2hh^T + bias2   (split, fp32-accurate)
      gather_split(L2buf, A_hi_s, A_lo_s, tid);
      __syncthreads();
      f32x4 ac0 = {0.f,0.f,0.f,0.f}, ac1 = {0.f,0.f,0.f,0.f};
      mm3g(A_hi_s, A_lo_s, W2ih_h, W2ih_l, r, lm, lq, ac0, ac1);
      __syncthreads();
      gather_split(H2buf + (size_t)(ci & 1)*8192, A_hi_s, A_lo_s, tid);
      __syncthreads();
      mm3g(A_hi_s, A_lo_s, W2hh_h, W2hh_l, r, lm, lq, ac0, ac1);
      #pragma unroll
      for (int i = 0; i < 4; ++i){
        int b0 = lq*4 + i;
        SGf[w*512 + b0*16 + lm]      = ac0[i] + b2v;
        SGf[w*512 + (b0+16)*16 + lm] = ac1[i] + b2v;
      }
      __syncthreads();
      // (h) layer-2 cell update, write up_x, post h2 to parity slot
      {
        float gi0 = SGf[bE*16+m0],      gi1 = SGf[bE*16+m1];
        float gf0 = SGf[512+bE*16+m0],  gf1 = SGf[512+bE*16+m1];
        float gg0 = SGf[1024+bE*16+m0], gg1 = SGf[1024+bE*16+m1];
        float go0 = SGf[1536+bE*16+m0], go1 = SGf[1536+bE*16+m1];
        float c2n0 = sigf(gf0)*cpa + sigf(gi0)*tanhf(gg0);
        float c2n1 = sigf(gf1)*cpb + sigf(gi1)*tanhf(gg1);
        float h2v0 = sigf(go0)*tanhf(c2n0);
        float h2v1 = sigf(go1)*tanhf(c2n1);
        c2a = c2n0; c2b = c2n1;
        upx[((size_t)ci*32 + bE)*256 + j*16 + m0] = h2v0;
        upx[((size_t)ci*32 + bE)*256 + j*16 + m1] = h2v1;
        size_t so = (size_t)((ci + 1) & 1)*8192;
        __hip_atomic_store(&H2buf[so + bE*256 + j*16 + m0], h2v0, __ATOMIC_RELAXED, AGT);
        __hip_atomic_store(&H2buf[so + bE*256 + j*16 + m1], h2v1, __ATOMIC_RELAXED, AGT);
      }
      __syncthreads();
    }

    // x-projection for step it+1 (overlaps flag propagation to other XCDs)
    if (it < 6399){
      const uint4* gh = (const uint4*)(Xhi + (size_t)(it + 1)*4096);
      const uint4* gl = (const uint4*)(Xlo + (size_t)(it + 1)*4096);
      #pragma unroll
      for (int q = 0; q < 4; ++q){
        ((uint4*)A_hi_s)[q*256 + tid] = gh[q*256 + tid];
        ((uint4*)A_lo_s)[q*256 + tid] = gl[q*256 + tid];
      }
      __syncthreads();
      xacc0 = (f32x4){0.f,0.f,0.f,0.f};
      xacc1 = (f32x4){0.f,0.f,0.f,0.f};
      mm3(A_hi_s, A_lo_s, Bih_h, Bih_l, lm, lq, xacc0, xacc1);
    }
  }
}

// ---------------- phase C: encoder attention + MLP head, one WG per batch ----------------
__global__ __launch_bounds__(256, 1) void out_k(
    const float* __restrict__ upx, const float* __restrict__ Wu,
    const float* __restrict__ bu, const float* __restrict__ We,
    const float* __restrict__ Wo1T, const float* __restrict__ bo1,
    const float* __restrict__ Wo2T, const float* __restrict__ bo2,
    float* __restrict__ out)
{
  __shared__ float sWu[128*257];
  __shared__ float sX[256];
  __shared__ float sPP[2][128];
  __shared__ float sU[128];
  __shared__ float sET[80*4];
  __shared__ float sW[80*4];
  __shared__ float sFlat[1024];
  __shared__ float sHid[512];
  const int b = blockIdx.x, tid = threadIdx.x;
  for (int i = tid; i < 32768; i += 256){ int a2 = i >> 8, k2 = i & 255; sWu[a2*257 + k2] = Wu[i]; }
  const int a = tid & 127, kh = tid >> 7;
  for (int l2 = 0; l2 < 80; ++l2){
    __syncthreads();
    sX[tid] = upx[((size_t)l2*32 + b)*256 + tid];
    __syncthreads();
    float acc = 0.f;
    #pragma unroll 4
    for (int k = 0; k < 128; ++k)
      acc += sWu[a*257 + kh*128 + k] * sX[kh*128 + k];
    sPP[kh][a] = acc;
    __syncthreads();
    if (tid < 128) sU[tid] = tanhf(sPP[0][tid] + sPP[1][tid] + bu[tid]);
    __syncthreads();
    if (tid < 4){
      float e = 0.f;
      for (int a2 = 0; a2 < 128; ++a2) e += We[tid*128 + a2] * sU[a2];
      sET[l2*4 + tid] = e;
    }
  }
  __syncthreads();
  if (tid < 4){
    float mx = -1e30f;
    for (int l2 = 0; l2 < 80; ++l2) mx = fmaxf(mx, sET[l2*4 + tid]);
    float s = 0.f;
    for (int l2 = 0; l2 < 80; ++l2){ float e = __expf(sET[l2*4+tid] - mx); sW[l2*4+tid] = e; s += e; }
    float inv = 1.f / s;
    for (int l2 = 0; l2 < 80; ++l2) sW[l2*4+tid] *= inv;
  }
  __syncthreads();
  float a0 = 0.f, a1 = 0.f, a2 = 0.f, a3 = 0.f;
  for (int l2 = 0; l2 < 80; ++l2){
    float xv = upx[((size_t)l2*32 + b)*256 + tid];
    a0 += sW[l2*4+0]*xv; a1 += sW[l2*4+1]*xv; a2 += sW[l2*4+2]*xv; a3 += sW[l2*4+3]*xv;
  }
  sFlat[tid] = a0; sFlat[256+tid] = a1; sFlat[512+tid] = a2; sFlat[768+tid] = a3;
  __syncthreads();
  #pragma unroll
  for (int h2 = 0; h2 < 2; ++h2){
    int n = tid + h2*256;
    float acc = bo1[n];
    for (int k = 0; k < 1024; ++k) acc += Wo1T[(size_t)k*512 + n] * sFlat[k];
    sHid[n] = fmaxf(acc, 0.f);
  }
  __syncthreads();
  {
    float acc = bo2[tid];
    for (int k = 0; k < 512; ++k) acc += Wo2T[(size_t)k*256 + tid] * sHid[k];
    out[b*256 + tid] = acc;
  }
}

// ---------------- launcher ----------------
extern "C" void kernel_launch(void* const* d_in, const int* in_sizes, int n_in,
                              void* d_out, int out_size, void* d_ws, size_t ws_size,
                              hipStream_t stream)
{
  (void)in_sizes; (void)n_in; (void)out_size;
  const float* x    = (const float*)d_in[0];
  const float* Wih1 = (const float*)d_in[1];
  const float* Whh1 = (const float*)d_in[2];
  const float* bih1 = (const float*)d_in[3];
  const float* bhh1 = (const float*)d_in[4];
  const float* Wih2 = (const float*)d_in[5];
  const float* Whh2 = (const float*)d_in[6];
  const float* bih2 = (const float*)d_in[7];
  const float* bhh2 = (const float*)d_in[8];
  const float* Wp   = (const float*)d_in[9];
  const float* Wu   = (const float*)d_in[11];
  const float* bu   = (const float*)d_in[12];
  const float* We   = (const float*)d_in[13];
  const float* Wo1  = (const float*)d_in[15];
  const float* bo1  = (const float*)d_in[16];
  const float* Wo2  = (const float*)d_in[17];
  const float* bo2  = (const float*)d_in[18];
  const float* h0   = (const float*)d_in[19];
  const float* c0   = (const float*)d_in[20];
  const float* h20  = (const float*)d_in[21];
  const float* c20  = (const float*)d_in[22];
  float* out = (float*)d_out;

  if (ws_size < 230000000ULL) return;   // need ~227 MB of scratch
  uint8_t* ws = (uint8_t*)d_ws;
  uint32_t* flags  = (uint32_t*)(ws + 0);
  uint32_t* flags2 = (uint32_t*)(ws + 512);
  uint16_t* W1ih_h = (uint16_t*)(ws + 4096);
  uint16_t* W1ih_l = (uint16_t*)(ws + 528384);
  uint16_t* W1hh_h = (uint16_t*)(ws + 1052672);
  uint16_t* W1hh_l = (uint16_t*)(ws + 1576960);
  uint16_t* W2ih_h = (uint16_t*)(ws + 2101248);
  uint16_t* W2ih_l = (uint16_t*)(ws + 2625536);
  uint16_t* W2hh_h = (uint16_t*)(ws + 3149824);
  uint16_t* W2hh_l = (uint16_t*)(ws + 3674112);
  float* bias1 = (float*)(ws + 4198400);
  float* bias2 = (float*)(ws + 4202496);
  float* Wo1T  = (float*)(ws + 4206592);
  float* Wo2T  = (float*)(ws + 6303744);
  float* upx   = (float*)(ws + 6828032);
  float* Pbuf  = (float*)(ws + 9449472);
  float* L2buf = (float*)(ws + 9779200);
  float* H2buf = (float*)(ws + 9811968);
  float* HistRing = (float*)(ws + 9877504);
  float* HcHist   = (float*)(ws + 9943040);
  uint32_t* Xhi = (uint32_t*)(ws + 16777216);
  uint32_t* Xlo = (uint32_t*)(ws + 121634816);

  hipMemsetAsync(ws, 0, 1024, stream);
  hipLaunchKernelGGL(prep_k, dim3(2048), dim3(256), 0, stream,
      Wih1, Whh1, bih1, bhh1, Wih2, Whh2, bih2, bhh2, Wo1, Wo2,
      W1ih_h, W1ih_l, W1hh_h, W1hh_l, W2ih_h, W2ih_l, W2hh_h, W2hh_l,
      bias1, bias2, Wo1T, Wo2T);
  hipLaunchKernelGGL(xsplit_k, dim3(6400), dim3(256), 0, stream, x, Xhi, Xlo);
  hipLaunchKernelGGL(scan_k, dim3(16), dim3(256), 0, stream,
      h0, c0, h20, c20, Wp,
      W1hh_h, W1hh_l, W1ih_h, W1ih_l,
      W2ih_h, W2ih_l, W2hh_h, W2hh_l,
      bias1, bias2, Xhi, Xlo,
      HistRing, flags, flags2, Pbuf, L2buf, H2buf, HcHist, upx);
  hipLaunchKernelGGL(out_k, dim3(32), dim3(256), 0, stream,
      upx, Wu, bu, We, Wo1T, bo1, Wo2T, bo2, out);
}

// Round 4
// 67752.435 us; speedup vs baseline: 1.1113x; 1.1113x over previous
//
#include <hip/hip_runtime.h>
#include <stdint.h>

#define AGT __HIP_MEMORY_SCOPE_AGENT
typedef unsigned long long u64;

typedef float f32x4 __attribute__((ext_vector_type(4)));
typedef short s16x8 __attribute__((ext_vector_type(8)));

__device__ __forceinline__ uint16_t f2bf(float f){
  union { float f; uint32_t u; } v; v.f = f;
  uint32_t r = v.u + 0x7FFFu + ((v.u >> 16) & 1u);
  return (uint16_t)(r >> 16);
}
__device__ __forceinline__ float bf2f(uint16_t u){
  union { uint32_t u; float f; } v; v.u = ((uint32_t)u) << 16; return v.f;
}
// split a,b into hi bf16 pair (returned) and lo residual bf16 pair (out param)
__device__ __forceinline__ uint32_t splitpack(float a, float b, uint32_t& lo){
  uint16_t ah = f2bf(a), bh = f2bf(b);
  float ar = a - bf2f(ah), br = b - bf2f(bh);
  lo = (uint32_t)f2bf(ar) | ((uint32_t)f2bf(br) << 16);
  return (uint32_t)ah | ((uint32_t)bh << 16);
}
// pack two f32 into u64 of (hi-pair, lo-pair)
__device__ __forceinline__ u64 splitpack64(float a, float b){
  uint32_t lo, hi = splitpack(a, b, lo);
  return (u64)hi | ((u64)lo << 32);
}
__device__ __forceinline__ float sigf(float x){ return 1.0f / (1.0f + __expf(-x)); }

__device__ __forceinline__ f32x4 MFMA16(s16x8 a, s16x8 b, f32x4 c){
  return __builtin_amdgcn_mfma_f32_16x16x32_bf16(a, b, c, 0, 0, 0);
}

// read a 16B A-fragment from swizzled LDS: row b, k-byte-offset kbyte (multiple of 16)
__device__ __forceinline__ s16x8 ldsA(const uint32_t* AH, int b, int kbyte){
  int off = b*512 + (kbyte ^ ((b & 7) << 4));
  return *(const s16x8*)((const uint8_t*)AH + off);
}

// gather a [4096] u64 (hi,lo packed) exchange buffer -> swizzled hi/lo LDS A-images
// (all loads relaxed agent-scope UC: read the coherence point directly, no cache maint.)
__device__ __forceinline__ void gather_u64(const u64* src, uint32_t* Ahi, uint32_t* Alo, int tid){
  #pragma unroll
  for (int i = 0; i < 16; ++i){
    int q = i*256 + tid;
    u64 v = __hip_atomic_load(&src[q], __ATOMIC_RELAXED, AGT);
    int b = q >> 7, p = q & 127;
    int off = b*512 + ((p*4) ^ ((b & 7) << 4));
    *(uint32_t*)((uint8_t*)Ahi + off) = (uint32_t)v;
    *(uint32_t*)((uint8_t*)Alo + off) = (uint32_t)(v >> 32);
  }
}

// 3-product split GEMM with register-resident B-fragments
__device__ __forceinline__ void mm3(const uint32_t* Ahi, const uint32_t* Alo,
                                    const s16x8* Bh, const s16x8* Bl,
                                    int lm, int lq, f32x4& a0, f32x4& a1){
  #pragma unroll
  for (int kt = 0; kt < 8; ++kt){
    int kb = kt*64 + lq*16;
    s16x8 h0v = ldsA(Ahi, lm, kb), h1v = ldsA(Ahi, 16 + lm, kb);
    s16x8 l0v = ldsA(Alo, lm, kb), l1v = ldsA(Alo, 16 + lm, kb);
    a0 = MFMA16(h0v, Bh[kt], a0);  a1 = MFMA16(h1v, Bh[kt], a1);
    a0 = MFMA16(h0v, Bl[kt], a0);  a1 = MFMA16(h1v, Bl[kt], a1);
    a0 = MFMA16(l0v, Bh[kt], a0);  a1 = MFMA16(l1v, Bh[kt], a1);
  }
}

// 3-product split GEMM with B-fragments loaded from global (used once per chunk)
__device__ __forceinline__ void mm3g(const uint32_t* Ahi, const uint32_t* Alo,
                                     const uint16_t* Wh, const uint16_t* Wl,
                                     int r, int lm, int lq, f32x4& a0, f32x4& a1){
  #pragma unroll
  for (int kt = 0; kt < 8; ++kt){
    size_t o = (size_t)r*256 + kt*32 + lq*8;
    s16x8 bh = *(const s16x8*)(Wh + o);
    s16x8 bl = *(const s16x8*)(Wl + o);
    int kb = kt*64 + lq*16;
    s16x8 h0v = ldsA(Ahi, lm, kb), h1v = ldsA(Ahi, 16 + lm, kb);
    s16x8 l0v = ldsA(Alo, lm, kb), l1v = ldsA(Alo, 16 + lm, kb);
    a0 = MFMA16(h0v, bh, a0);  a1 = MFMA16(h1v, bh, a1);
    a0 = MFMA16(h0v, bl, a0);  a1 = MFMA16(h1v, bl, a1);
    a0 = MFMA16(l0v, bh, a0);  a1 = MFMA16(l1v, bh, a1);
  }
}

// ---------------- prep: split weights to bf16 hi/lo, fused biases, head transposes ----------------
__global__ __launch_bounds__(256) void prep_k(
    const float* __restrict__ Wih1, const float* __restrict__ Whh1,
    const float* __restrict__ bih1, const float* __restrict__ bhh1,
    const float* __restrict__ Wih2, const float* __restrict__ Whh2,
    const float* __restrict__ bih2, const float* __restrict__ bhh2,
    const float* __restrict__ Wo1, const float* __restrict__ Wo2,
    uint16_t* __restrict__ W1ih_h, uint16_t* __restrict__ W1ih_l,
    uint16_t* __restrict__ W1hh_h, uint16_t* __restrict__ W1hh_l,
    uint16_t* __restrict__ W2ih_h, uint16_t* __restrict__ W2ih_l,
    uint16_t* __restrict__ W2hh_h, uint16_t* __restrict__ W2hh_l,
    float* __restrict__ bias1, float* __restrict__ bias2,
    float* __restrict__ Wo1T, float* __restrict__ Wo2T)
{
  int i = blockIdx.x * 256 + threadIdx.x;
  if (i < 262144){
    float w; uint16_t h;
    w = Wih1[i]; h = f2bf(w); W1ih_h[i] = h; W1ih_l[i] = f2bf(w - bf2f(h));
    w = Whh1[i]; h = f2bf(w); W1hh_h[i] = h; W1hh_l[i] = f2bf(w - bf2f(h));
    w = Wih2[i]; h = f2bf(w); W2ih_h[i] = h; W2ih_l[i] = f2bf(w - bf2f(h));
    w = Whh2[i]; h = f2bf(w); W2hh_h[i] = h; W2hh_l[i] = f2bf(w - bf2f(h));
  }
  if (i < 1024){ bias1[i] = bih1[i] + bhh1[i]; bias2[i] = bih2[i] + bhh2[i]; }
  if (i < 524288){ Wo1T[i] = Wo1[(size_t)(i & 511)*1024 + (i >> 9)]; }
  if (i < 131072){ Wo2T[i] = Wo2[(size_t)(i & 255)*512 + (i >> 8)]; }
}

// ---------------- xsplit: x -> per-t swizzled LDS-image hi/lo planes ----------------
__global__ __launch_bounds__(256, 1) void xsplit_k(
    const float* __restrict__ x, uint32_t* __restrict__ Xhi, uint32_t* __restrict__ Xlo)
{
  __shared__ uint32_t HI[4096];
  __shared__ uint32_t LO[4096];
  const int t = blockIdx.x, tid = threadIdx.x;
  const int b = tid >> 3, seg = tid & 7;
  const float4* xr = (const float4*)(x + ((size_t)b*6400 + t)*256 + seg*32);
  #pragma unroll
  for (int ii = 0; ii < 8; ++ii){
    float4 v = xr[ii];
    int p0 = seg*16 + ii*2;
    uint32_t lo0, lo1;
    uint32_t hi0 = splitpack(v.x, v.y, lo0);
    uint32_t hi1 = splitpack(v.z, v.w, lo1);
    int o0 = (b*512 + (((p0  )*4) ^ ((b&7)<<4))) >> 2;
    int o1 = (b*512 + (((p0+1)*4) ^ ((b&7)<<4))) >> 2;
    HI[o0] = hi0; LO[o0] = lo0;
    HI[o1] = hi1; LO[o1] = lo1;
  }
  __syncthreads();
  uint4* gh = (uint4*)(Xhi + (size_t)t*4096);
  uint4* gl = (uint4*)(Xlo + (size_t)t*4096);
  const uint4* sh = (const uint4*)HI;
  const uint4* sl = (const uint4*)LO;
  #pragma unroll
  for (int q = 0; q < 4; ++q){
    gh[q*256 + tid] = sh[q*256 + tid];
    gl[q*256 + tid] = sl[q*256 + tid];
  }
}

// ---------------- phase B: persistent 16-WG flag-synced scan (fp32-accurate) ----------------
// All cross-WG exchange is RELAXED agent-scope (UC -> MALL coherence point, no wbl2/inv).
// Ordering: data stores are drained by the vmcnt(0) inside __syncthreads() BEFORE the
// flag store; consumer polls the flag then reads data with UC loads.
__global__ __launch_bounds__(256, 1) void scan_k(
    const float* __restrict__ h0, const float* __restrict__ c0,
    const float* __restrict__ h20, const float* __restrict__ c20,
    const float* __restrict__ Wp,
    const uint16_t* __restrict__ W1hh_h, const uint16_t* __restrict__ W1hh_l,
    const uint16_t* __restrict__ W1ih_h, const uint16_t* __restrict__ W1ih_l,
    const uint16_t* __restrict__ W2ih_h, const uint16_t* __restrict__ W2ih_l,
    const uint16_t* __restrict__ W2hh_h, const uint16_t* __restrict__ W2hh_l,
    const float* __restrict__ bias1, const float* __restrict__ bias2,
    const uint32_t* __restrict__ Xhi, const uint32_t* __restrict__ Xlo,
    u64* HistRing, uint32_t* flags, uint32_t* flags2,
    float* Pbuf, u64* L2buf, u64* H2buf, float* HcHist, float* upx)
{
  __shared__ uint32_t A_hi_s[4096];          // [32][256] bf16-hi swizzled (16KB)
  __shared__ uint32_t A_lo_s[4096];          // lo residual (16KB)
  __shared__ float SGf[2048];                // [4 gates][32 b][16 m] f32 (8KB) + scratch
  __shared__ float PH[2560];                 // [80][32] h score partials
  __shared__ float PC[2560];                 // [80][32] c score partials

  const int j = blockIdx.x;
  const int tid = threadIdx.x;
  const int w = tid >> 6;                    // wave == gate index (i,f,g,o)
  const int l = tid & 63;
  const int lm = l & 15, lq = l >> 4;
  const int bE = tid >> 3, mp = tid & 7;
  const int m0 = 2*mp, m1 = m0 + 1;

  // resident B-fragments for W_hh1 and W_ih1 (hi+lo)
  const int r = w*256 + j*16 + lm;
  s16x8 Bhh_h[8], Bhh_l[8], Bih_h[8], Bih_l[8];
  #pragma unroll
  for (int kt = 0; kt < 8; ++kt){
    size_t o = (size_t)r*256 + kt*32 + lq*8;
    Bhh_h[kt] = *(const s16x8*)(W1hh_h + o);
    Bhh_l[kt] = *(const s16x8*)(W1hh_l + o);
    Bih_h[kt] = *(const s16x8*)(W1ih_h + o);
    Bih_l[kt] = *(const s16x8*)(W1ih_l + o);
  }
  const float b1v = bias1[r];
  const float b2v = bias2[r];
  const float wp0 = Wp[j*16 + m0];
  const float wp1 = Wp[j*16 + m1];

  float c1a = c0[bE*256 + j*16 + m0];
  float c1b = c0[bE*256 + j*16 + m1];
  float c2a = c20[bE*256 + j*16 + m0];
  float c2b = c20[bE*256 + j*16 + m1];

  // init H2buf parity-slot 0 and HistRing slot 0 (own slice, packed hi/lo)
  __hip_atomic_store(&H2buf[bE*128 + j*8 + mp],
      splitpack64(h20[bE*256 + j*16 + m0], h20[bE*256 + j*16 + m1]), __ATOMIC_RELAXED, AGT);
  __hip_atomic_store(&HistRing[bE*128 + j*8 + mp],
      splitpack64(h0[bE*256 + j*16 + m0], h0[bE*256 + j*16 + m1]), __ATOMIC_RELAXED, AGT);
  __syncthreads();                            // drains vmcnt -> stores at coherence point
  if (tid == 0) __hip_atomic_store(&flags[j], 1u, __ATOMIC_RELAXED, AGT);

  // prologue: x-projection accumulator for step 0
  f32x4 xacc0 = {0.f,0.f,0.f,0.f}, xacc1 = {0.f,0.f,0.f,0.f};
  {
    const uint4* gh = (const uint4*)Xhi;
    const uint4* gl = (const uint4*)Xlo;
    #pragma unroll
    for (int q = 0; q < 4; ++q){
      ((uint4*)A_hi_s)[q*256 + tid] = gh[q*256 + tid];
      ((uint4*)A_lo_s)[q*256 + tid] = gl[q*256 + tid];
    }
    __syncthreads();
    mm3(A_hi_s, A_lo_s, Bih_h, Bih_l, lm, lq, xacc0, xacc1);
  }

  float* hh = HcHist + (size_t)j*81920;

  for (int it = 0; it < 6400; ++it){
    const int lch = it % 80;
    if (tid < 16){
      while (__hip_atomic_load(&flags[tid], __ATOMIC_RELAXED, AGT) < (uint32_t)(it + 1))
        __builtin_amdgcn_s_sleep(1);
    }
    __syncthreads();
    gather_u64(HistRing + (size_t)(it & 1)*4096, A_hi_s, A_lo_s, tid);
    __syncthreads();
    // gates = x-part (carried) + h @ Whh1^T  (split, fp32-accurate)
    f32x4 acc0 = xacc0, acc1 = xacc1;
    mm3(A_hi_s, A_lo_s, Bhh_h, Bhh_l, lm, lq, acc0, acc1);
    #pragma unroll
    for (int i = 0; i < 4; ++i){
      int b0 = lq*4 + i;
      SGf[w*512 + b0*16 + lm]      = acc0[i] + b1v;
      SGf[w*512 + (b0+16)*16 + lm] = acc1[i] + b1v;
    }
    __syncthreads();
    // elementwise LSTM update + fp32 private history + packed exchange post + pooling partials
    {
      float gi0 = SGf[bE*16+m0],      gi1 = SGf[bE*16+m1];
      float gf0 = SGf[512+bE*16+m0],  gf1 = SGf[512+bE*16+m1];
      float gg0 = SGf[1024+bE*16+m0], gg1 = SGf[1024+bE*16+m1];
      float go0 = SGf[1536+bE*16+m0], go1 = SGf[1536+bE*16+m1];
      float cn0 = sigf(gf0)*c1a + sigf(gi0)*tanhf(gg0);
      float cn1 = sigf(gf1)*c1b + sigf(gi1)*tanhf(gg1);
      float hn0 = sigf(go0)*tanhf(cn0);
      float hn1 = sigf(go1)*tanhf(cn1);
      c1a = cn0; c1b = cn1;
      int o = (lch*32 + bE)*16;
      hh[o + m0] = hn0; hh[o + m1] = hn1;
      hh[40960 + o + m0] = cn0; hh[40960 + o + m1] = cn1;
      int sl = (it + 1) & 1;
      __hip_atomic_store(&HistRing[(size_t)sl*4096 + bE*128 + j*8 + mp],
                         splitpack64(hn0, hn1), __ATOMIC_RELAXED, AGT);
      float ph = hn0*wp0 + hn1*wp1;
      float pc = cn0*wp0 + cn1*wp1;
      ph += __shfl_xor(ph, 1); ph += __shfl_xor(ph, 2); ph += __shfl_xor(ph, 4);
      pc += __shfl_xor(pc, 1); pc += __shfl_xor(pc, 2); pc += __shfl_xor(pc, 4);
      if (mp == 0){ PH[lch*32 + bE] = ph; PC[lch*32 + bE] = pc; }
    }
    __syncthreads();                          // drains vmcnt (h store at coherence point)
    if (tid == 0) __hip_atomic_store(&flags[j], (uint32_t)(it + 2), __ATOMIC_RELAXED, AGT);

    if (lch == 79){
      const int ci = it / 80;
      // (a) post score partials + c2 partial
      for (int x2 = tid; x2 < 2560; x2 += 256){
        __hip_atomic_store(&Pbuf[j*5152 + x2],        PH[x2], __ATOMIC_RELAXED, AGT);
        __hip_atomic_store(&Pbuf[j*5152 + 2560 + x2], PC[x2], __ATOMIC_RELAXED, AGT);
      }
      {
        float pc2 = c2a*wp0 + c2b*wp1;
        pc2 += __shfl_xor(pc2, 1); pc2 += __shfl_xor(pc2, 2); pc2 += __shfl_xor(pc2, 4);
        if (mp == 0) __hip_atomic_store(&Pbuf[j*5152 + 5120 + bE], pc2, __ATOMIC_RELAXED, AGT);
      }
      __syncthreads();
      if (tid == 0) __hip_atomic_store(&flags2[j], (uint32_t)(2*ci + 1), __ATOMIC_RELAXED, AGT);
      if (tid < 16){
        while (__hip_atomic_load(&flags2[tid], __ATOMIC_RELAXED, AGT) < (uint32_t)(2*ci + 1))
          __builtin_amdgcn_s_sleep(1);
      }
      __syncthreads();
      // (b) sum partials across WGs
      for (int x2 = tid; x2 < 5152; x2 += 256){
        float s = 0.f;
        #pragma unroll
        for (int k = 0; k < 16; ++k)
          s += __hip_atomic_load(&Pbuf[k*5152 + x2], __ATOMIC_RELAXED, AGT);
        if (x2 < 2560) PH[x2] = s;
        else if (x2 < 5120) PC[x2 - 2560] = s;
        else SGf[x2 - 5120] = s;            // sc2[b]
      }
      __syncthreads();
      // (c) softmax (redundant per WG)
      if (tid < 32){
        int b = tid;
        float mx = -1e30f;
        for (int l2 = 0; l2 < 80; ++l2) mx = fmaxf(mx, PH[l2*32 + b]);
        float s = 0.f;
        for (int l2 = 0; l2 < 80; ++l2){ float e = __expf(PH[l2*32+b] - mx); PH[l2*32+b] = e; s += e; }
        float inv = 1.f / s;
        for (int l2 = 0; l2 < 80; ++l2) PH[l2*32+b] *= inv;
        float mc = SGf[b];
        for (int l2 = 0; l2 < 80; ++l2) mc = fmaxf(mc, PC[l2*32 + b]);
        s = 0.f;
        for (int l2 = 0; l2 < 80; ++l2){ float e = __expf(PC[l2*32+b] - mc); PC[l2*32+b] = e; s += e; }
        float e81 = __expf(SGf[b] - mc); s += e81;
        inv = 1.f / s;
        for (int l2 = 0; l2 < 80; ++l2) PC[l2*32+b] *= inv;
        SGf[32 + b] = e81 * inv;
      }
      __syncthreads();
      // (d)+(f) pooled c2 and l2_in from fp32 private history; post l2_in packed
      float cpa = 0.f, cpb = 0.f, la = 0.f, lb = 0.f;
      for (int l2 = 0; l2 < 80; ++l2){
        float whv = PH[l2*32 + bE], wcv = PC[l2*32 + bE];
        int o = (l2*32 + bE)*16;
        la  += whv * hh[o + m0];          lb  += whv * hh[o + m1];
        cpa += wcv * hh[40960 + o + m0];  cpb += wcv * hh[40960 + o + m1];
      }
      { float w81 = SGf[32 + bE]; cpa += w81 * c2a; cpb += w81 * c2b; }
      __hip_atomic_store(&L2buf[bE*128 + j*8 + mp], splitpack64(la, lb), __ATOMIC_RELAXED, AGT);
      __syncthreads();
      if (tid == 0) __hip_atomic_store(&flags2[j], (uint32_t)(2*ci + 2), __ATOMIC_RELAXED, AGT);
      if (tid < 16){
        while (__hip_atomic_load(&flags2[tid], __ATOMIC_RELAXED, AGT) < (uint32_t)(2*ci + 2))
          __builtin_amdgcn_s_sleep(1);
      }
      __syncthreads();
      // (g) gates2 = l2_in@W2ih^T + h2@W2hh^T + bias2   (split, fp32-accurate)
      gather_u64(L2buf, A_hi_s, A_lo_s, tid);
      __syncthreads();
      f32x4 ac0 = {0.f,0.f,0.f,0.f}, ac1 = {0.f,0.f,0.f,0.f};
      mm3g(A_hi_s, A_lo_s, W2ih_h, W2ih_l, r, lm, lq, ac0, ac1);
      __syncthreads();
      gather_u64(H2buf + (size_t)(ci & 1)*4096, A_hi_s, A_lo_s, tid);
      __syncthreads();
      mm3g(A_hi_s, A_lo_s, W2hh_h, W2hh_l, r, lm, lq, ac0, ac1);
      #pragma unroll
      for (int i = 0; i < 4; ++i){
        int b0 = lq*4 + i;
        SGf[w*512 + b0*16 + lm]      = ac0[i] + b2v;
        SGf[w*512 + (b0+16)*16 + lm] = ac1[i] + b2v;
      }
      __syncthreads();
      // (h) layer-2 cell update, write up_x, post h2 to parity slot
      {
        float gi0 = SGf[bE*16+m0],      gi1 = SGf[bE*16+m1];
        float gf0 = SGf[512+bE*16+m0],  gf1 = SGf[512+bE*16+m1];
        float gg0 = SGf[1024+bE*16+m0], gg1 = SGf[1024+bE*16+m1];
        float go0 = SGf[1536+bE*16+m0], go1 = SGf[1536+bE*16+m1];
        float c2n0 = sigf(gf0)*cpa + sigf(gi0)*tanhf(gg0);
        float c2n1 = sigf(gf1)*cpb + sigf(gi1)*tanhf(gg1);
        float h2v0 = sigf(go0)*tanhf(c2n0);
        float h2v1 = sigf(go1)*tanhf(c2n1);
        c2a = c2n0; c2b = c2n1;
        upx[((size_t)ci*32 + bE)*256 + j*16 + m0] = h2v0;
        upx[((size_t)ci*32 + bE)*256 + j*16 + m1] = h2v1;
        __hip_atomic_store(&H2buf[(size_t)((ci + 1) & 1)*4096 + bE*128 + j*8 + mp],
                           splitpack64(h2v0, h2v1), __ATOMIC_RELAXED, AGT);
      }
      __syncthreads();
    }

    // x-projection for step it+1 (overlaps flag propagation to other XCDs)
    if (it < 6399){
      const uint4* gh = (const uint4*)(Xhi + (size_t)(it + 1)*4096);
      const uint4* gl = (const uint4*)(Xlo + (size_t)(it + 1)*4096);
      #pragma unroll
      for (int q = 0; q < 4; ++q){
        ((uint4*)A_hi_s)[q*256 + tid] = gh[q*256 + tid];
        ((uint4*)A_lo_s)[q*256 + tid] = gl[q*256 + tid];
      }
      __syncthreads();
      xacc0 = (f32x4){0.f,0.f,0.f,0.f};
      xacc1 = (f32x4){0.f,0.f,0.f,0.f};
      mm3(A_hi_s, A_lo_s, Bih_h, Bih_l, lm, lq, xacc0, xacc1);
    }
  }
}

// ---------------- phase C: encoder attention + MLP head, one WG per batch ----------------
__global__ __launch_bounds__(256, 1) void out_k(
    const float* __restrict__ upx, const float* __restrict__ Wu,
    const float* __restrict__ bu, const float* __restrict__ We,
    const float* __restrict__ Wo1T, const float* __restrict__ bo1,
    const float* __restrict__ Wo2T, const float* __restrict__ bo2,
    float* __restrict__ out)
{
  __shared__ float sWu[128*257];
  __shared__ float sX[256];
  __shared__ float sPP[2][128];
  __shared__ float sU[128];
  __shared__ float sET[80*4];
  __shared__ float sW[80*4];
  __shared__ float sFlat[1024];
  __shared__ float sHid[512];
  const int b = blockIdx.x, tid = threadIdx.x;
  for (int i = tid; i < 32768; i += 256){ int a2 = i >> 8, k2 = i & 255; sWu[a2*257 + k2] = Wu[i]; }
  const int a = tid & 127, kh = tid >> 7;
  for (int l2 = 0; l2 < 80; ++l2){
    __syncthreads();
    sX[tid] = upx[((size_t)l2*32 + b)*256 + tid];
    __syncthreads();
    float acc = 0.f;
    #pragma unroll 4
    for (int k = 0; k < 128; ++k)
      acc += sWu[a*257 + kh*128 + k] * sX[kh*128 + k];
    sPP[kh][a] = acc;
    __syncthreads();
    if (tid < 128) sU[tid] = tanhf(sPP[0][tid] + sPP[1][tid] + bu[tid]);
    __syncthreads();
    if (tid < 4){
      float e = 0.f;
      for (int a2 = 0; a2 < 128; ++a2) e += We[tid*128 + a2] * sU[a2];
      sET[l2*4 + tid] = e;
    }
  }
  __syncthreads();
  if (tid < 4){
    float mx = -1e30f;
    for (int l2 = 0; l2 < 80; ++l2) mx = fmaxf(mx, sET[l2*4 + tid]);
    float s = 0.f;
    for (int l2 = 0; l2 < 80; ++l2){ float e = __expf(sET[l2*4+tid] - mx); sW[l2*4+tid] = e; s += e; }
    float inv = 1.f / s;
    for (int l2 = 0; l2 < 80; ++l2) sW[l2*4+tid] *= inv;
  }
  __syncthreads();
  float a0 = 0.f, a1 = 0.f, a2 = 0.f, a3 = 0.f;
  for (int l2 = 0; l2 < 80; ++l2){
    float xv = upx[((size_t)l2*32 + b)*256 + tid];
    a0 += sW[l2*4+0]*xv; a1 += sW[l2*4+1]*xv; a2 += sW[l2*4+2]*xv; a3 += sW[l2*4+3]*xv;
  }
  sFlat[tid] = a0; sFlat[256+tid] = a1; sFlat[512+tid] = a2; sFlat[768+tid] = a3;
  __syncthreads();
  #pragma unroll
  for (int h2 = 0; h2 < 2; ++h2){
    int n = tid + h2*256;
    float acc = bo1[n];
    for (int k = 0; k < 1024; ++k) acc += Wo1T[(size_t)k*512 + n] * sFlat[k];
    sHid[n] = fmaxf(acc, 0.f);
  }
  __syncthreads();
  {
    float acc = bo2[tid];
    for (int k = 0; k < 512; ++k) acc += Wo2T[(size_t)k*256 + tid] * sHid[k];
    out[b*256 + tid] = acc;
  }
}

// ---------------- launcher ----------------
extern "C" void kernel_launch(void* const* d_in, const int* in_sizes, int n_in,
                              void* d_out, int out_size, void* d_ws, size_t ws_size,
                              hipStream_t stream)
{
  (void)in_sizes; (void)n_in; (void)out_size;
  const float* x    = (const float*)d_in[0];
  const float* Wih1 = (const float*)d_in[1];
  const float* Whh1 = (const float*)d_in[2];
  const float* bih1 = (const float*)d_in[3];
  const float* bhh1 = (const float*)d_in[4];
  const float* Wih2 = (const float*)d_in[5];
  const float* Whh2 = (const float*)d_in[6];
  const float* bih2 = (const float*)d_in[7];
  const float* bhh2 = (const float*)d_in[8];
  const float* Wp   = (const float*)d_in[9];
  const float* Wu   = (const float*)d_in[11];
  const float* bu   = (const float*)d_in[12];
  const float* We   = (const float*)d_in[13];
  const float* Wo1  = (const float*)d_in[15];
  const float* bo1  = (const float*)d_in[16];
  const float* Wo2  = (const float*)d_in[17];
  const float* bo2  = (const float*)d_in[18];
  const float* h0   = (const float*)d_in[19];
  const float* c0   = (const float*)d_in[20];
  const float* h20  = (const float*)d_in[21];
  const float* c20  = (const float*)d_in[22];
  float* out = (float*)d_out;

  if (ws_size < 230000000ULL) return;   // need ~227 MB of scratch
  uint8_t* ws = (uint8_t*)d_ws;
  uint32_t* flags  = (uint32_t*)(ws + 0);
  uint32_t* flags2 = (uint32_t*)(ws + 512);
  uint16_t* W1ih_h = (uint16_t*)(ws + 4096);
  uint16_t* W1ih_l = (uint16_t*)(ws + 528384);
  uint16_t* W1hh_h = (uint16_t*)(ws + 1052672);
  uint16_t* W1hh_l = (uint16_t*)(ws + 1576960);
  uint16_t* W2ih_h = (uint16_t*)(ws + 2101248);
  uint16_t* W2ih_l = (uint16_t*)(ws + 2625536);
  uint16_t* W2hh_h = (uint16_t*)(ws + 3149824);
  uint16_t* W2hh_l = (uint16_t*)(ws + 3674112);
  float* bias1 = (float*)(ws + 4198400);
  float* bias2 = (float*)(ws + 4202496);
  float* Wo1T  = (float*)(ws + 4206592);
  float* Wo2T  = (float*)(ws + 6303744);
  float* upx   = (float*)(ws + 6828032);
  float* Pbuf  = (float*)(ws + 9449472);
  u64*   L2buf = (u64*)(ws + 9779200);
  u64*   H2buf = (u64*)(ws + 9811968);
  u64*   HistRing = (u64*)(ws + 9877504);
  float* HcHist   = (float*)(ws + 9943040);
  uint32_t* Xhi = (uint32_t*)(ws + 16777216);
  uint32_t* Xlo = (uint32_t*)(ws + 121634816);

  hipMemsetAsync(ws, 0, 1024, stream);
  hipLaunchKernelGGL(prep_k, dim3(2048), dim3(256), 0, stream,
      Wih1, Whh1, bih1, bhh1, Wih2, Whh2, bih2, bhh2, Wo1, Wo2,
      W1ih_h, W1ih_l, W1hh_h, W1hh_l, W2ih_h, W2ih_l, W2hh_h, W2hh_l,
      bias1, bias2, Wo1T, Wo2T);
  hipLaunchKernelGGL(xsplit_k, dim3(6400), dim3(256), 0, stream, x, Xhi, Xlo);
  hipLaunchKernelGGL(scan_k, dim3(16), dim3(256), 0, stream,
      h0, c0, h20, c20, Wp,
      W1hh_h, W1hh_l, W1ih_h, W1ih_l,
      W2ih_h, W2ih_l, W2hh_h, W2hh_l,
      bias1, bias2, Xhi, Xlo,
      HistRing, flags, flags2, Pbuf, L2buf, H2buf, HcHist, upx);
  hipLaunchKernelGGL(out_k, dim3(32), dim3(256), 0, stream,
      upx, Wu, bu, We, Wo1T, bo1, Wo2T, bo2, out);
}

// Round 7
// 55916.785 us; speedup vs baseline: 1.3465x; 1.2117x over previous
//
#include <hip/hip_runtime.h>
#include <stdint.h>

#define AGT __HIP_MEMORY_SCOPE_AGENT
typedef unsigned long long u64;

typedef float f32x4 __attribute__((ext_vector_type(4)));
typedef short s16x8 __attribute__((ext_vector_type(8)));
typedef uint32_t u32x4 __attribute__((ext_vector_type(4)));

__device__ __forceinline__ uint16_t f2bf(float f){
  union { float f; uint32_t u; } v; v.f = f;
  uint32_t r = v.u + 0x7FFFu + ((v.u >> 16) & 1u);
  return (uint16_t)(r >> 16);
}
__device__ __forceinline__ float bf2f(uint16_t u){
  union { uint32_t u; float f; } v; v.u = ((uint32_t)u) << 16; return v.f;
}
__device__ __forceinline__ uint32_t splitpack(float a, float b, uint32_t& lo){
  uint16_t ah = f2bf(a), bh = f2bf(b);
  float ar = a - bf2f(ah), br = b - bf2f(bh);
  lo = (uint32_t)f2bf(ar) | ((uint32_t)f2bf(br) << 16);
  return (uint32_t)ah | ((uint32_t)bh << 16);
}
__device__ __forceinline__ u64 splitpack64(float a, float b){
  uint32_t lo, hi = splitpack(a, b, lo);
  return (u64)hi | ((u64)lo << 32);
}
__device__ __forceinline__ float sigf(float x){ return 1.0f / (1.0f + __expf(-x)); }

__device__ __forceinline__ f32x4 MFMA16(s16x8 a, s16x8 b, f32x4 c){
  return __builtin_amdgcn_mfma_f32_16x16x32_bf16(a, b, c, 0, 0, 0);
}

__device__ __forceinline__ s16x8 ldsA(const uint32_t* AH, int b, int kbyte){
  int off = b*512 + (kbyte ^ ((b & 7) << 4));
  return *(const s16x8*)((const uint8_t*)AH + off);
}

// ---- MALL-coherent tagged-unit primitives (sc0+sc1: chip-coherent, bypass L0/L2) ----
// store one 16B unit, fire-and-forget
__device__ __forceinline__ void st16_uc(u32x4* p, u32x4 v){
  asm volatile("global_store_dwordx4 %0, %1, off sc0 sc1" :: "v"(p), "v"(v) : "memory");
}
// 8 coherent 16B loads (stride 256 units), self-contained wait (waitcnt inside the block)
__device__ __forceinline__ void ld8t(const u32x4* b, int off0, u32x4* v){
  const u32x4 *p0=b+off0,      *p1=b+off0+256,  *p2=b+off0+512,  *p3=b+off0+768,
              *p4=b+off0+1024, *p5=b+off0+1280, *p6=b+off0+1536, *p7=b+off0+1792;
  asm volatile(
    "global_load_dwordx4 %0, %8, off sc0 sc1\n\t"
    "global_load_dwordx4 %1, %9, off sc0 sc1\n\t"
    "global_load_dwordx4 %2, %10, off sc0 sc1\n\t"
    "global_load_dwordx4 %3, %11, off sc0 sc1\n\t"
    "global_load_dwordx4 %4, %12, off sc0 sc1\n\t"
    "global_load_dwordx4 %5, %13, off sc0 sc1\n\t"
    "global_load_dwordx4 %6, %14, off sc0 sc1\n\t"
    "global_load_dwordx4 %7, %15, off sc0 sc1\n\t"
    "s_waitcnt vmcnt(0)"
    : "=&v"(v[0]), "=&v"(v[1]), "=&v"(v[2]), "=&v"(v[3]),
      "=&v"(v[4]), "=&v"(v[5]), "=&v"(v[6]), "=&v"(v[7])
    : "v"(p0), "v"(p1), "v"(p2), "v"(p3), "v"(p4), "v"(p5), "v"(p6), "v"(p7)
    : "memory");
}

// tag-polled gather of a step's h-exchange ring slot -> swizzled hi/lo LDS A-images.
// unit q=(b*128+p): {hi-pair, tag, lo-pair, tag}; accept when both tags match.
__device__ __forceinline__ void gather_tag(const u32x4* ring, uint32_t tag,
                                           uint32_t* Ahi, uint32_t* Alo, int tid){
  u32x4 v[8];
  #pragma unroll 1
  for (int h = 0; h < 2; ++h){
    const int off0 = h*2048 + tid;
    ld8t(ring, off0, v);
    while (true){
      uint32_t bad = 0;
      #pragma unroll
      for (int i = 0; i < 8; ++i) bad |= (v[i][1] ^ tag) | (v[i][3] ^ tag);
      if (!bad) break;
      __builtin_amdgcn_s_sleep(1);
      ld8t(ring, off0, v);
    }
    #pragma unroll
    for (int i = 0; i < 8; ++i){
      int q = (h*8 + i)*256 + tid; int b = q >> 7, p = q & 127;
      int off = b*512 + ((p*4) ^ ((b & 7) << 4));
      *(uint32_t*)((uint8_t*)Ahi + off) = v[i][0];
      *(uint32_t*)((uint8_t*)Alo + off) = v[i][2];
    }
  }
}

// gather a [4096] u64 (hi,lo packed) exchange buffer -> swizzled hi/lo LDS A-images (AGT relaxed)
__device__ __forceinline__ void gather_u64(const u64* src, uint32_t* Ahi, uint32_t* Alo, int tid){
  #pragma unroll
  for (int i = 0; i < 16; ++i){
    int q = i*256 + tid;
    u64 v = __hip_atomic_load(&src[q], __ATOMIC_RELAXED, AGT);
    int b = q >> 7, p = q & 127;
    int off = b*512 + ((p*4) ^ ((b & 7) << 4));
    *(uint32_t*)((uint8_t*)Ahi + off) = (uint32_t)v;
    *(uint32_t*)((uint8_t*)Alo + off) = (uint32_t)(v >> 32);
  }
}

__device__ __forceinline__ void mm3(const uint32_t* Ahi, const uint32_t* Alo,
                                    const s16x8* Bh, const s16x8* Bl,
                                    int lm, int lq, f32x4& a0, f32x4& a1){
  #pragma unroll
  for (int kt = 0; kt < 8; ++kt){
    int kb = kt*64 + lq*16;
    s16x8 h0v = ldsA(Ahi, lm, kb), h1v = ldsA(Ahi, 16 + lm, kb);
    s16x8 l0v = ldsA(Alo, lm, kb), l1v = ldsA(Alo, 16 + lm, kb);
    a0 = MFMA16(h0v, Bh[kt], a0);  a1 = MFMA16(h1v, Bh[kt], a1);
    a0 = MFMA16(h0v, Bl[kt], a0);  a1 = MFMA16(h1v, Bl[kt], a1);
    a0 = MFMA16(l0v, Bh[kt], a0);  a1 = MFMA16(l1v, Bh[kt], a1);
  }
}

__device__ __forceinline__ void mm3g(const uint32_t* Ahi, const uint32_t* Alo,
                                     const uint16_t* Wh, const uint16_t* Wl,
                                     int r, int lm, int lq, f32x4& a0, f32x4& a1){
  #pragma unroll
  for (int kt = 0; kt < 8; ++kt){
    size_t o = (size_t)r*256 + kt*32 + lq*8;
    s16x8 bh = *(const s16x8*)(Wh + o);
    s16x8 bl = *(const s16x8*)(Wl + o);
    int kb = kt*64 + lq*16;
    s16x8 h0v = ldsA(Ahi, lm, kb), h1v = ldsA(Ahi, 16 + lm, kb);
    s16x8 l0v = ldsA(Alo, lm, kb), l1v = ldsA(Alo, 16 + lm, kb);
    a0 = MFMA16(h0v, bh, a0);  a1 = MFMA16(h1v, bh, a1);
    a0 = MFMA16(h0v, bl, a0);  a1 = MFMA16(h1v, bl, a1);
    a0 = MFMA16(l0v, bh, a0);  a1 = MFMA16(l1v, bh, a1);
  }
}

// ---------------- prep ----------------
__global__ __launch_bounds__(256) void prep_k(
    const float* __restrict__ Wih1, const float* __restrict__ Whh1,
    const float* __restrict__ bih1, const float* __restrict__ bhh1,
    const float* __restrict__ Wih2, const float* __restrict__ Whh2,
    const float* __restrict__ bih2, const float* __restrict__ bhh2,
    const float* __restrict__ Wo1, const float* __restrict__ Wo2,
    uint16_t* __restrict__ W1ih_h, uint16_t* __restrict__ W1ih_l,
    uint16_t* __restrict__ W1hh_h, uint16_t* __restrict__ W1hh_l,
    uint16_t* __restrict__ W2ih_h, uint16_t* __restrict__ W2ih_l,
    uint16_t* __restrict__ W2hh_h, uint16_t* __restrict__ W2hh_l,
    float* __restrict__ bias1, float* __restrict__ bias2,
    float* __restrict__ Wo1T, float* __restrict__ Wo2T)
{
  int i = blockIdx.x * 256 + threadIdx.x;
  if (i < 262144){
    float w; uint16_t h;
    w = Wih1[i]; h = f2bf(w); W1ih_h[i] = h; W1ih_l[i] = f2bf(w - bf2f(h));
    w = Whh1[i]; h = f2bf(w); W1hh_h[i] = h; W1hh_l[i] = f2bf(w - bf2f(h));
    w = Wih2[i]; h = f2bf(w); W2ih_h[i] = h; W2ih_l[i] = f2bf(w - bf2f(h));
    w = Whh2[i]; h = f2bf(w); W2hh_h[i] = h; W2hh_l[i] = f2bf(w - bf2f(h));
  }
  if (i < 1024){ bias1[i] = bih1[i] + bhh1[i]; bias2[i] = bih2[i] + bhh2[i]; }
  if (i < 524288){ Wo1T[i] = Wo1[(size_t)(i & 511)*1024 + (i >> 9)]; }
  if (i < 131072){ Wo2T[i] = Wo2[(size_t)(i & 255)*512 + (i >> 8)]; }
}

// ---------------- xsplit ----------------
__global__ __launch_bounds__(256, 1) void xsplit_k(
    const float* __restrict__ x, uint32_t* __restrict__ Xhi, uint32_t* __restrict__ Xlo)
{
  __shared__ uint32_t HI[4096];
  __shared__ uint32_t LO[4096];
  const int t = blockIdx.x, tid = threadIdx.x;
  const int b = tid >> 3, seg = tid & 7;
  const float4* xr = (const float4*)(x + ((size_t)b*6400 + t)*256 + seg*32);
  #pragma unroll
  for (int ii = 0; ii < 8; ++ii){
    float4 v = xr[ii];
    int p0 = seg*16 + ii*2;
    uint32_t lo0, lo1;
    uint32_t hi0 = splitpack(v.x, v.y, lo0);
    uint32_t hi1 = splitpack(v.z, v.w, lo1);
    int o0 = (b*512 + (((p0  )*4) ^ ((b&7)<<4))) >> 2;
    int o1 = (b*512 + (((p0+1)*4) ^ ((b&7)<<4))) >> 2;
    HI[o0] = hi0; LO[o0] = lo0;
    HI[o1] = hi1; LO[o1] = lo1;
  }
  __syncthreads();
  uint4* gh = (uint4*)(Xhi + (size_t)t*4096);
  uint4* gl = (uint4*)(Xlo + (size_t)t*4096);
  const uint4* sh = (const uint4*)HI;
  const uint4* sl = (const uint4*)LO;
  #pragma unroll
  for (int q = 0; q < 4; ++q){
    gh[q*256 + tid] = sh[q*256 + tid];
    gl[q*256 + tid] = sl[q*256 + tid];
  }
}

// ---------------- phase B: persistent 16-WG scan, tag-in-data exchange (no flags) ----------------
__global__ __launch_bounds__(256, 1) void scan_k(
    const float* __restrict__ h0, const float* __restrict__ c0,
    const float* __restrict__ h20, const float* __restrict__ c20,
    const float* __restrict__ Wp,
    const uint16_t* __restrict__ W1hh_h, const uint16_t* __restrict__ W1hh_l,
    const uint16_t* __restrict__ W1ih_h, const uint16_t* __restrict__ W1ih_l,
    const uint16_t* __restrict__ W2ih_h, const uint16_t* __restrict__ W2ih_l,
    const uint16_t* __restrict__ W2hh_h, const uint16_t* __restrict__ W2hh_l,
    const float* __restrict__ bias1, const float* __restrict__ bias2,
    const uint32_t* __restrict__ Xhi, const uint32_t* __restrict__ Xlo,
    u32x4* Ring, uint32_t* flags2,
    float* Pbuf, u64* L2buf, u64* H2buf, float* HcHist, float* upx)
{
  __shared__ uint32_t A_hi_s[4096];
  __shared__ uint32_t A_lo_s[4096];
  __shared__ float SGf[2048];
  __shared__ float PH[2560];
  __shared__ float PC[2560];

  const int j = blockIdx.x;
  const int tid = threadIdx.x;
  const int w = tid >> 6;
  const int l = tid & 63;
  const int lm = l & 15, lq = l >> 4;
  const int bE = tid >> 3, mp = tid & 7;
  const int m0 = 2*mp, m1 = m0 + 1;

  const int r = w*256 + j*16 + lm;
  s16x8 Bhh_h[8], Bhh_l[8], Bih_h[8], Bih_l[8];
  #pragma unroll
  for (int kt = 0; kt < 8; ++kt){
    size_t o = (size_t)r*256 + kt*32 + lq*8;
    Bhh_h[kt] = *(const s16x8*)(W1hh_h + o);
    Bhh_l[kt] = *(const s16x8*)(W1hh_l + o);
    Bih_h[kt] = *(const s16x8*)(W1ih_h + o);
    Bih_l[kt] = *(const s16x8*)(W1ih_l + o);
  }
  const float b1v = bias1[r];
  const float b2v = bias2[r];
  const float wp0 = Wp[j*16 + m0];
  const float wp1 = Wp[j*16 + m1];

  float c1a = c0[bE*256 + j*16 + m0];
  float c1b = c0[bE*256 + j*16 + m1];
  float c2a = c20[bE*256 + j*16 + m0];
  float c2b = c20[bE*256 + j*16 + m1];

  // init: H2buf parity-slot 0 (AGT, chunk-rate) and tagged h0 publish (tag=1, slot 0)
  __hip_atomic_store(&H2buf[bE*128 + j*8 + mp],
      splitpack64(h20[bE*256 + j*16 + m0], h20[bE*256 + j*16 + m1]), __ATOMIC_RELAXED, AGT);
  {
    uint32_t lo, hi = splitpack(h0[bE*256 + j*16 + m0], h0[bE*256 + j*16 + m1], lo);
    u32x4 u; u[0] = hi; u[1] = 1u; u[2] = lo; u[3] = 1u;
    st16_uc(Ring + bE*128 + j*8 + mp, u);
  }

  // prologue: x-projection accumulator for step 0
  f32x4 xacc0 = {0.f,0.f,0.f,0.f}, xacc1 = {0.f,0.f,0.f,0.f};
  {
    const uint4* gh = (const uint4*)Xhi;
    const uint4* gl = (const uint4*)Xlo;
    #pragma unroll
    for (int q = 0; q < 4; ++q){
      ((uint4*)A_hi_s)[q*256 + tid] = gh[q*256 + tid];
      ((uint4*)A_lo_s)[q*256 + tid] = gl[q*256 + tid];
    }
    __syncthreads();
    mm3(A_hi_s, A_lo_s, Bih_h, Bih_l, lm, lq, xacc0, xacc1);
  }

  float* hh = HcHist + (size_t)j*81920;

  for (int it = 0; it < 6400; ++it){
    const int lch = it % 80;
    __syncthreads();                       // protect A_* from prefetch readers
    gather_tag(Ring + (size_t)(it & 1)*4096, (uint32_t)(it + 1), A_hi_s, A_lo_s, tid);
    __syncthreads();
    f32x4 acc0 = xacc0, acc1 = xacc1;
    mm3(A_hi_s, A_lo_s, Bhh_h, Bhh_l, lm, lq, acc0, acc1);
    #pragma unroll
    for (int i = 0; i < 4; ++i){
      int b0 = lq*4 + i;
      SGf[w*512 + b0*16 + lm]      = acc0[i] + b1v;
      SGf[w*512 + (b0+16)*16 + lm] = acc1[i] + b1v;
    }
    __syncthreads();
    {
      float gi0 = SGf[bE*16+m0],      gi1 = SGf[bE*16+m1];
      float gf0 = SGf[512+bE*16+m0],  gf1 = SGf[512+bE*16+m1];
      float gg0 = SGf[1024+bE*16+m0], gg1 = SGf[1024+bE*16+m1];
      float go0 = SGf[1536+bE*16+m0], go1 = SGf[1536+bE*16+m1];
      float cn0 = sigf(gf0)*c1a + sigf(gi0)*tanhf(gg0);
      float cn1 = sigf(gf1)*c1b + sigf(gi1)*tanhf(gg1);
      float hn0 = sigf(go0)*tanhf(cn0);
      float hn1 = sigf(go1)*tanhf(cn1);
      c1a = cn0; c1b = cn1;
      // fire-and-forget tagged publish of h[it+1] (tag = it+2)
      {
        uint32_t lo, hi = splitpack(hn0, hn1, lo);
        u32x4 u; u[0] = hi; u[1] = (uint32_t)(it + 2); u[2] = lo; u[3] = (uint32_t)(it + 2);
        st16_uc(Ring + (size_t)((it + 1) & 1)*4096 + bE*128 + j*8 + mp, u);
      }
      int o = (lch*32 + bE)*16;
      hh[o + m0] = hn0; hh[o + m1] = hn1;
      hh[40960 + o + m0] = cn0; hh[40960 + o + m1] = cn1;
      float ph = hn0*wp0 + hn1*wp1;
      float pc = cn0*wp0 + cn1*wp1;
      ph += __shfl_xor(ph, 1); ph += __shfl_xor(ph, 2); ph += __shfl_xor(ph, 4);
      pc += __shfl_xor(pc, 1); pc += __shfl_xor(pc, 2); pc += __shfl_xor(pc, 4);
      if (mp == 0){ PH[lch*32 + bE] = ph; PC[lch*32 + bE] = pc; }
    }
    __syncthreads();

    if (lch == 79){
      const int ci = it / 80;
      for (int x2 = tid; x2 < 2560; x2 += 256){
        __hip_atomic_store(&Pbuf[j*5152 + x2],        PH[x2], __ATOMIC_RELAXED, AGT);
        __hip_atomic_store(&Pbuf[j*5152 + 2560 + x2], PC[x2], __ATOMIC_RELAXED, AGT);
      }
      {
        float pc2 = c2a*wp0 + c2b*wp1;
        pc2 += __shfl_xor(pc2, 1); pc2 += __shfl_xor(pc2, 2); pc2 += __shfl_xor(pc2, 4);
        if (mp == 0) __hip_atomic_store(&Pbuf[j*5152 + 5120 + bE], pc2, __ATOMIC_RELAXED, AGT);
      }
      __syncthreads();
      if (tid == 0) __hip_atomic_store(&flags2[j], (uint32_t)(2*ci + 1), __ATOMIC_RELAXED, AGT);
      if (tid < 16){
        while (__hip_atomic_load(&flags2[tid], __ATOMIC_RELAXED, AGT) < (uint32_t)(2*ci + 1))
          __builtin_amdgcn_s_sleep(1);
      }
      __syncthreads();
      for (int x2 = tid; x2 < 5152; x2 += 256){
        float s = 0.f;
        #pragma unroll
        for (int k = 0; k < 16; ++k)
          s += __hip_atomic_load(&Pbuf[k*5152 + x2], __ATOMIC_RELAXED, AGT);
        if (x2 < 2560) PH[x2] = s;
        else if (x2 < 5120) PC[x2 - 2560] = s;
        else SGf[x2 - 5120] = s;
      }
      __syncthreads();
      if (tid < 32){
        int b = tid;
        float mx = -1e30f;
        for (int l2 = 0; l2 < 80; ++l2) mx = fmaxf(mx, PH[l2*32 + b]);
        float s = 0.f;
        for (int l2 = 0; l2 < 80; ++l2){ float e = __expf(PH[l2*32+b] - mx); PH[l2*32+b] = e; s += e; }
        float inv = 1.f / s;
        for (int l2 = 0; l2 < 80; ++l2) PH[l2*32+b] *= inv;
        float mc = SGf[b];
        for (int l2 = 0; l2 < 80; ++l2) mc = fmaxf(mc, PC[l2*32 + b]);
        s = 0.f;
        for (int l2 = 0; l2 < 80; ++l2){ float e = __expf(PC[l2*32+b] - mc); PC[l2*32+b] = e; s += e; }
        float e81 = __expf(SGf[b] - mc); s += e81;
        inv = 1.f / s;
        for (int l2 = 0; l2 < 80; ++l2) PC[l2*32+b] *= inv;
        SGf[32 + b] = e81 * inv;
      }
      __syncthreads();
      float cpa = 0.f, cpb = 0.f, la = 0.f, lb = 0.f;
      for (int l2 = 0; l2 < 80; ++l2){
        float whv = PH[l2*32 + bE], wcv = PC[l2*32 + bE];
        int o = (l2*32 + bE)*16;
        la  += whv * hh[o + m0];          lb  += whv * hh[o + m1];
        cpa += wcv * hh[40960 + o + m0];  cpb += wcv * hh[40960 + o + m1];
      }
      { float w81 = SGf[32 + bE]; cpa += w81 * c2a; cpb += w81 * c2b; }
      __hip_atomic_store(&L2buf[bE*128 + j*8 + mp], splitpack64(la, lb), __ATOMIC_RELAXED, AGT);
      __syncthreads();
      if (tid == 0) __hip_atomic_store(&flags2[j], (uint32_t)(2*ci + 2), __ATOMIC_RELAXED, AGT);
      if (tid < 16){
        while (__hip_atomic_load(&flags2[tid], __ATOMIC_RELAXED, AGT) < (uint32_t)(2*ci + 2))
          __builtin_amdgcn_s_sleep(1);
      }
      __syncthreads();
      gather_u64(L2buf, A_hi_s, A_lo_s, tid);
      __syncthreads();
      f32x4 ac0 = {0.f,0.f,0.f,0.f}, ac1 = {0.f,0.f,0.f,0.f};
      mm3g(A_hi_s, A_lo_s, W2ih_h, W2ih_l, r, lm, lq, ac0, ac1);
      __syncthreads();
      gather_u64(H2buf + (size_t)(ci & 1)*4096, A_hi_s, A_lo_s, tid);
      __syncthreads();
      mm3g(A_hi_s, A_lo_s, W2hh_h, W2hh_l, r, lm, lq, ac0, ac1);
      #pragma unroll
      for (int i = 0; i < 4; ++i){
        int b0 = lq*4 + i;
        SGf[w*512 + b0*16 + lm]      = ac0[i] + b2v;
        SGf[w*512 + (b0+16)*16 + lm] = ac1[i] + b2v;
      }
      __syncthreads();
      {
        float gi0 = SGf[bE*16+m0],      gi1 = SGf[bE*16+m1];
        float gf0 = SGf[512+bE*16+m0],  gf1 = SGf[512+bE*16+m1];
        float gg0 = SGf[1024+bE*16+m0], gg1 = SGf[1024+bE*16+m1];
        float go0 = SGf[1536+bE*16+m0], go1 = SGf[1536+bE*16+m1];
        float c2n0 = sigf(gf0)*cpa + sigf(gi0)*tanhf(gg0);
        float c2n1 = sigf(gf1)*cpb + sigf(gi1)*tanhf(gg1);
        float h2v0 = sigf(go0)*tanhf(c2n0);
        float h2v1 = sigf(go1)*tanhf(c2n1);
        c2a = c2n0; c2b = c2n1;
        upx[((size_t)ci*32 + bE)*256 + j*16 + m0] = h2v0;
        upx[((size_t)ci*32 + bE)*256 + j*16 + m1] = h2v1;
        __hip_atomic_store(&H2buf[(size_t)((ci + 1) & 1)*4096 + bE*128 + j*8 + mp],
                           splitpack64(h2v0, h2v1), __ATOMIC_RELAXED, AGT);
      }
      __syncthreads();
    }

    if (it < 6399){
      const uint4* gh = (const uint4*)(Xhi + (size_t)(it + 1)*4096);
      const uint4* gl = (const uint4*)(Xlo + (size_t)(it + 1)*4096);
      #pragma unroll
      for (int q = 0; q < 4; ++q){
        ((uint4*)A_hi_s)[q*256 + tid] = gh[q*256 + tid];
        ((uint4*)A_lo_s)[q*256 + tid] = gl[q*256 + tid];
      }
      __syncthreads();
      xacc0 = (f32x4){0.f,0.f,0.f,0.f};
      xacc1 = (f32x4){0.f,0.f,0.f,0.f};
      mm3(A_hi_s, A_lo_s, Bih_h, Bih_l, lm, lq, xacc0, xacc1);
    }
  }
}

// ---------------- phase C: encoder attention + MLP head ----------------
__global__ __launch_bounds__(256, 1) void out_k(
    const float* __restrict__ upx, const float* __restrict__ Wu,
    const float* __restrict__ bu, const float* __restrict__ We,
    const float* __restrict__ Wo1T, const float* __restrict__ bo1,
    const float* __restrict__ Wo2T, const float* __restrict__ bo2,
    float* __restrict__ out)
{
  __shared__ float sWu[128*257];
  __shared__ float sX[256];
  __shared__ float sPP[2][128];
  __shared__ float sU[128];
  __shared__ float sET[80*4];
  __shared__ float sW[80*4];
  __shared__ float sFlat[1024];
  __shared__ float sHid[512];
  const int b = blockIdx.x, tid = threadIdx.x;
  for (int i = tid; i < 32768; i += 256){ int a2 = i >> 8, k2 = i & 255; sWu[a2*257 + k2] = Wu[i]; }
  const int a = tid & 127, kh = tid >> 7;
  for (int l2 = 0; l2 < 80; ++l2){
    __syncthreads();
    sX[tid] = upx[((size_t)l2*32 + b)*256 + tid];
    __syncthreads();
    float acc = 0.f;
    #pragma unroll 4
    for (int k = 0; k < 128; ++k)
      acc += sWu[a*257 + kh*128 + k] * sX[kh*128 + k];
    sPP[kh][a] = acc;
    __syncthreads();
    if (tid < 128) sU[tid] = tanhf(sPP[0][tid] + sPP[1][tid] + bu[tid]);
    __syncthreads();
    if (tid < 4){
      float e = 0.f;
      for (int a2 = 0; a2 < 128; ++a2) e += We[tid*128 + a2] * sU[a2];
      sET[l2*4 + tid] = e;
    }
  }
  __syncthreads();
  if (tid < 4){
    float mx = -1e30f;
    for (int l2 = 0; l2 < 80; ++l2) mx = fmaxf(mx, sET[l2*4 + tid]);
    float s = 0.f;
    for (int l2 = 0; l2 < 80; ++l2){ float e = __expf(sET[l2*4+tid] - mx); sW[l2*4+tid] = e; s += e; }
    float inv = 1.f / s;
    for (int l2 = 0; l2 < 80; ++l2) sW[l2*4+tid] *= inv;
  }
  __syncthreads();
  float a0 = 0.f, a1 = 0.f, a2 = 0.f, a3 = 0.f;
  for (int l2 = 0; l2 < 80; ++l2){
    float xv = upx[((size_t)l2*32 + b)*256 + tid];
    a0 += sW[l2*4+0]*xv; a1 += sW[l2*4+1]*xv; a2 += sW[l2*4+2]*xv; a3 += sW[l2*4+3]*xv;
  }
  sFlat[tid] = a0; sFlat[256+tid] = a1; sFlat[512+tid] = a2; sFlat[768+tid] = a3;
  __syncthreads();
  #pragma unroll
  for (int h2 = 0; h2 < 2; ++h2){
    int n = tid + h2*256;
    float acc = bo1[n];
    for (int k = 0; k < 1024; ++k) acc += Wo1T[(size_t)k*512 + n] * sFlat[k];
    sHid[n] = fmaxf(acc, 0.f);
  }
  __syncthreads();
  {
    float acc = bo2[tid];
    for (int k = 0; k < 512; ++k) acc += Wo2T[(size_t)k*256 + tid] * sHid[k];
    out[b*256 + tid] = acc;
  }
}

// ---------------- launcher ----------------
extern "C" void kernel_launch(void* const* d_in, const int* in_sizes, int n_in,
                              void* d_out, int out_size, void* d_ws, size_t ws_size,
                              hipStream_t stream)
{
  (void)in_sizes; (void)n_in; (void)out_size;
  const float* x    = (const float*)d_in[0];
  const float* Wih1 = (const float*)d_in[1];
  const float* Whh1 = (const float*)d_in[2];
  const float* bih1 = (const float*)d_in[3];
  const float* bhh1 = (const float*)d_in[4];
  const float* Wih2 = (const float*)d_in[5];
  const float* Whh2 = (const float*)d_in[6];
  const float* bih2 = (const float*)d_in[7];
  const float* bhh2 = (const float*)d_in[8];
  const float* Wp   = (const float*)d_in[9];
  const float* Wu   = (const float*)d_in[11];
  const float* bu   = (const float*)d_in[12];
  const float* We   = (const float*)d_in[13];
  const float* Wo1  = (const float*)d_in[15];
  const float* bo1  = (const float*)d_in[16];
  const float* Wo2  = (const float*)d_in[17];
  const float* bo2  = (const float*)d_in[18];
  const float* h0   = (const float*)d_in[19];
  const float* c0   = (const float*)d_in[20];
  const float* h20  = (const float*)d_in[21];
  const float* c20  = (const float*)d_in[22];
  float* out = (float*)d_out;

  if (ws_size < 230000000ULL) return;
  uint8_t* ws = (uint8_t*)d_ws;
  uint32_t* flags2 = (uint32_t*)(ws + 512);
  uint16_t* W1ih_h = (uint16_t*)(ws + 4096);
  uint16_t* W1ih_l = (uint16_t*)(ws + 528384);
  uint16_t* W1hh_h = (uint16_t*)(ws + 1052672);
  uint16_t* W1hh_l = (uint16_t*)(ws + 1576960);
  uint16_t* W2ih_h = (uint16_t*)(ws + 2101248);
  uint16_t* W2ih_l = (uint16_t*)(ws + 2625536);
  uint16_t* W2hh_h = (uint16_t*)(ws + 3149824);
  uint16_t* W2hh_l = (uint16_t*)(ws + 3674112);
  float* bias1 = (float*)(ws + 4198400);
  float* bias2 = (float*)(ws + 4202496);
  float* Wo1T  = (float*)(ws + 4206592);
  float* Wo2T  = (float*)(ws + 6303744);
  float* upx   = (float*)(ws + 6828032);
  float* Pbuf  = (float*)(ws + 9449472);
  u64*   L2buf = (u64*)(ws + 9779200);
  u64*   H2buf = (u64*)(ws + 9811968);
  float* HcHist   = (float*)(ws + 9943040);
  u32x4* Ring  = (u32x4*)(ws + 15728640);   // 2 slots x 4096 units x 16B = 128KB
  uint32_t* Xhi = (uint32_t*)(ws + 16777216);
  uint32_t* Xlo = (uint32_t*)(ws + 121634816);

  (void)hipMemsetAsync(ws, 0, 4096, stream);               // flags2
  (void)hipMemsetAsync(ws + 15728640, 0, 131072, stream);  // Ring tags (replay-safe)
  hipLaunchKernelGGL(prep_k, dim3(2048), dim3(256), 0, stream,
      Wih1, Whh1, bih1, bhh1, Wih2, Whh2, bih2, bhh2, Wo1, Wo2,
      W1ih_h, W1ih_l, W1hh_h, W1hh_l, W2ih_h, W2ih_l, W2hh_h, W2hh_l,
      bias1, bias2, Wo1T, Wo2T);
  hipLaunchKernelGGL(xsplit_k, dim3(6400), dim3(256), 0, stream, x, Xhi, Xlo);
  hipLaunchKernelGGL(scan_k, dim3(16), dim3(256), 0, stream,
      h0, c0, h20, c20, Wp,
      W1hh_h, W1hh_l, W1ih_h, W1ih_l,
      W2ih_h, W2ih_l, W2hh_h, W2hh_l,
      bias1, bias2, Xhi, Xlo,
      Ring, flags2, Pbuf, L2buf, H2buf, HcHist, upx);
  hipLaunchKernelGGL(out_k, dim3(32), dim3(256), 0, stream,
      upx, Wu, bu, We, Wo1T, bo1, Wo2T, bo2, out);
}

// Round 8
// 44898.184 us; speedup vs baseline: 1.6770x; 1.2454x over previous
//
#include <hip/hip_runtime.h>
#include <stdint.h>

#define AGT __HIP_MEMORY_SCOPE_AGENT
typedef unsigned long long u64;

typedef float f32x4 __attribute__((ext_vector_type(4)));
typedef short s16x8 __attribute__((ext_vector_type(8)));
typedef uint32_t u32x4 __attribute__((ext_vector_type(4)));

__device__ __forceinline__ uint16_t f2bf(float f){
  union { float f; uint32_t u; } v; v.f = f;
  uint32_t r = v.u + 0x7FFFu + ((v.u >> 16) & 1u);
  return (uint16_t)(r >> 16);
}
__device__ __forceinline__ float bf2f(uint16_t u){
  union { uint32_t u; float f; } v; v.u = ((uint32_t)u) << 16; return v.f;
}
__device__ __forceinline__ uint32_t splitpack(float a, float b, uint32_t& lo){
  uint16_t ah = f2bf(a), bh = f2bf(b);
  float ar = a - bf2f(ah), br = b - bf2f(bh);
  lo = (uint32_t)f2bf(ar) | ((uint32_t)f2bf(br) << 16);
  return (uint32_t)ah | ((uint32_t)bh << 16);
}
__device__ __forceinline__ u64 splitpack64(float a, float b){
  uint32_t lo, hi = splitpack(a, b, lo);
  return (u64)hi | ((u64)lo << 32);
}
__device__ __forceinline__ float sigf(float x){ return 1.0f / (1.0f + __expf(-x)); }

__device__ __forceinline__ f32x4 MFMA16(s16x8 a, s16x8 b, f32x4 c){
  return __builtin_amdgcn_mfma_f32_16x16x32_bf16(a, b, c, 0, 0, 0);
}

__device__ __forceinline__ s16x8 ldsA(const uint32_t* AH, int b, int kbyte){
  int off = b*512 + (kbyte ^ ((b & 7) << 4));
  return *(const s16x8*)((const uint8_t*)AH + off);
}

// ---- MALL-coherent tagged-unit primitives (sc0+sc1: chip-coherent, bypass L0/L2) ----
__device__ __forceinline__ void st16_uc(u32x4* p, u32x4 v){
  asm volatile("global_store_dwordx4 %0, %1, off sc0 sc1" :: "v"(p), "v"(v) : "memory");
}
// 16 coherent 16B loads (stride 256 units), ONE self-contained wait
__device__ __forceinline__ void ld16t(const u32x4* b, int tid, u32x4* v){
  const u32x4 *p0=b+tid,         *p1=b+tid+256,   *p2=b+tid+512,   *p3=b+tid+768,
              *p4=b+tid+1024,    *p5=b+tid+1280,  *p6=b+tid+1536,  *p7=b+tid+1792,
              *p8=b+tid+2048,    *p9=b+tid+2304,  *pa=b+tid+2560,  *pb=b+tid+2816,
              *pc=b+tid+3072,    *pd=b+tid+3328,  *pe=b+tid+3584,  *pf=b+tid+3840;
  asm volatile(
    "global_load_dwordx4 %0, %16, off sc0 sc1\n\t"
    "global_load_dwordx4 %1, %17, off sc0 sc1\n\t"
    "global_load_dwordx4 %2, %18, off sc0 sc1\n\t"
    "global_load_dwordx4 %3, %19, off sc0 sc1\n\t"
    "global_load_dwordx4 %4, %20, off sc0 sc1\n\t"
    "global_load_dwordx4 %5, %21, off sc0 sc1\n\t"
    "global_load_dwordx4 %6, %22, off sc0 sc1\n\t"
    "global_load_dwordx4 %7, %23, off sc0 sc1\n\t"
    "global_load_dwordx4 %8, %24, off sc0 sc1\n\t"
    "global_load_dwordx4 %9, %25, off sc0 sc1\n\t"
    "global_load_dwordx4 %10, %26, off sc0 sc1\n\t"
    "global_load_dwordx4 %11, %27, off sc0 sc1\n\t"
    "global_load_dwordx4 %12, %28, off sc0 sc1\n\t"
    "global_load_dwordx4 %13, %29, off sc0 sc1\n\t"
    "global_load_dwordx4 %14, %30, off sc0 sc1\n\t"
    "global_load_dwordx4 %15, %31, off sc0 sc1\n\t"
    "s_waitcnt vmcnt(0)"
    : "=&v"(v[0]), "=&v"(v[1]), "=&v"(v[2]), "=&v"(v[3]),
      "=&v"(v[4]), "=&v"(v[5]), "=&v"(v[6]), "=&v"(v[7]),
      "=&v"(v[8]), "=&v"(v[9]), "=&v"(v[10]), "=&v"(v[11]),
      "=&v"(v[12]), "=&v"(v[13]), "=&v"(v[14]), "=&v"(v[15])
    : "v"(p0), "v"(p1), "v"(p2), "v"(p3), "v"(p4), "v"(p5), "v"(p6), "v"(p7),
      "v"(p8), "v"(p9), "v"(pa), "v"(pb), "v"(pc), "v"(pd), "v"(pe), "v"(pf)
    : "memory");
}

// single-batch tag-polled gather: unit {hi, tag, lo, tag}; accept when all 32 tag words match.
__device__ __forceinline__ void gather_tag16(const u32x4* ring, uint32_t tag,
                                             uint32_t* Ahi, uint32_t* Alo, int tid){
  u32x4 v[16];
  ld16t(ring, tid, v);
  while (true){
    uint32_t bad = 0;
    #pragma unroll
    for (int i = 0; i < 16; ++i) bad |= (v[i][1] ^ tag) | (v[i][3] ^ tag);
    if (!bad) break;
    __builtin_amdgcn_s_sleep(1);
    ld16t(ring, tid, v);
  }
  #pragma unroll
  for (int i = 0; i < 16; ++i){
    int q = i*256 + tid; int b = q >> 7, p = q & 127;
    int off = b*512 + ((p*4) ^ ((b & 7) << 4));
    *(uint32_t*)((uint8_t*)Ahi + off) = v[i][0];
    *(uint32_t*)((uint8_t*)Alo + off) = v[i][2];
  }
}

// gather a [4096] u64 (hi,lo packed) exchange buffer -> swizzled hi/lo LDS A-images (AGT relaxed)
__device__ __forceinline__ void gather_u64(const u64* src, uint32_t* Ahi, uint32_t* Alo, int tid){
  #pragma unroll
  for (int i = 0; i < 16; ++i){
    int q = i*256 + tid;
    u64 v = __hip_atomic_load(&src[q], __ATOMIC_RELAXED, AGT);
    int b = q >> 7, p = q & 127;
    int off = b*512 + ((p*4) ^ ((b & 7) << 4));
    *(uint32_t*)((uint8_t*)Ahi + off) = (uint32_t)v;
    *(uint32_t*)((uint8_t*)Alo + off) = (uint32_t)(v >> 32);
  }
}

__device__ __forceinline__ void mm3(const uint32_t* Ahi, const uint32_t* Alo,
                                    const s16x8* Bh, const s16x8* Bl,
                                    int lm, int lq, f32x4& a0, f32x4& a1){
  #pragma unroll
  for (int kt = 0; kt < 8; ++kt){
    int kb = kt*64 + lq*16;
    s16x8 h0v = ldsA(Ahi, lm, kb), h1v = ldsA(Ahi, 16 + lm, kb);
    s16x8 l0v = ldsA(Alo, lm, kb), l1v = ldsA(Alo, 16 + lm, kb);
    a0 = MFMA16(h0v, Bh[kt], a0);  a1 = MFMA16(h1v, Bh[kt], a1);
    a0 = MFMA16(h0v, Bl[kt], a0);  a1 = MFMA16(h1v, Bl[kt], a1);
    a0 = MFMA16(l0v, Bh[kt], a0);  a1 = MFMA16(l1v, Bh[kt], a1);
  }
}

__device__ __forceinline__ void mm3g(const uint32_t* Ahi, const uint32_t* Alo,
                                     const uint16_t* Wh, const uint16_t* Wl,
                                     int r, int lm, int lq, f32x4& a0, f32x4& a1){
  #pragma unroll
  for (int kt = 0; kt < 8; ++kt){
    size_t o = (size_t)r*256 + kt*32 + lq*8;
    s16x8 bh = *(const s16x8*)(Wh + o);
    s16x8 bl = *(const s16x8*)(Wl + o);
    int kb = kt*64 + lq*16;
    s16x8 h0v = ldsA(Ahi, lm, kb), h1v = ldsA(Ahi, 16 + lm, kb);
    s16x8 l0v = ldsA(Alo, lm, kb), l1v = ldsA(Alo, 16 + lm, kb);
    a0 = MFMA16(h0v, bh, a0);  a1 = MFMA16(h1v, bh, a1);
    a0 = MFMA16(h0v, bl, a0);  a1 = MFMA16(h1v, bl, a1);
    a0 = MFMA16(l0v, bh, a0);  a1 = MFMA16(l1v, bh, a1);
  }
}

// ---------------- prep ----------------
__global__ __launch_bounds__(256) void prep_k(
    const float* __restrict__ Wih1, const float* __restrict__ Whh1,
    const float* __restrict__ bih1, const float* __restrict__ bhh1,
    const float* __restrict__ Wih2, const float* __restrict__ Whh2,
    const float* __restrict__ bih2, const float* __restrict__ bhh2,
    const float* __restrict__ Wo1, const float* __restrict__ Wo2,
    uint16_t* __restrict__ W1ih_h, uint16_t* __restrict__ W1ih_l,
    uint16_t* __restrict__ W1hh_h, uint16_t* __restrict__ W1hh_l,
    uint16_t* __restrict__ W2ih_h, uint16_t* __restrict__ W2ih_l,
    uint16_t* __restrict__ W2hh_h, uint16_t* __restrict__ W2hh_l,
    float* __restrict__ bias1, float* __restrict__ bias2,
    float* __restrict__ Wo1T, float* __restrict__ Wo2T)
{
  int i = blockIdx.x * 256 + threadIdx.x;
  if (i < 262144){
    float w; uint16_t h;
    w = Wih1[i]; h = f2bf(w); W1ih_h[i] = h; W1ih_l[i] = f2bf(w - bf2f(h));
    w = Whh1[i]; h = f2bf(w); W1hh_h[i] = h; W1hh_l[i] = f2bf(w - bf2f(h));
    w = Wih2[i]; h = f2bf(w); W2ih_h[i] = h; W2ih_l[i] = f2bf(w - bf2f(h));
    w = Whh2[i]; h = f2bf(w); W2hh_h[i] = h; W2hh_l[i] = f2bf(w - bf2f(h));
  }
  if (i < 1024){ bias1[i] = bih1[i] + bhh1[i]; bias2[i] = bih2[i] + bhh2[i]; }
  if (i < 524288){ Wo1T[i] = Wo1[(size_t)(i & 511)*1024 + (i >> 9)]; }
  if (i < 131072){ Wo2T[i] = Wo2[(size_t)(i & 255)*512 + (i >> 8)]; }
}

// ---------------- xsplit ----------------
__global__ __launch_bounds__(256, 1) void xsplit_k(
    const float* __restrict__ x, uint32_t* __restrict__ Xhi, uint32_t* __restrict__ Xlo)
{
  __shared__ uint32_t HI[4096];
  __shared__ uint32_t LO[4096];
  const int t = blockIdx.x, tid = threadIdx.x;
  const int b = tid >> 3, seg = tid & 7;
  const float4* xr = (const float4*)(x + ((size_t)b*6400 + t)*256 + seg*32);
  #pragma unroll
  for (int ii = 0; ii < 8; ++ii){
    float4 v = xr[ii];
    int p0 = seg*16 + ii*2;
    uint32_t lo0, lo1;
    uint32_t hi0 = splitpack(v.x, v.y, lo0);
    uint32_t hi1 = splitpack(v.z, v.w, lo1);
    int o0 = (b*512 + (((p0  )*4) ^ ((b&7)<<4))) >> 2;
    int o1 = (b*512 + (((p0+1)*4) ^ ((b&7)<<4))) >> 2;
    HI[o0] = hi0; LO[o0] = lo0;
    HI[o1] = hi1; LO[o1] = lo1;
  }
  __syncthreads();
  uint4* gh = (uint4*)(Xhi + (size_t)t*4096);
  uint4* gl = (uint4*)(Xlo + (size_t)t*4096);
  const uint4* sh = (const uint4*)HI;
  const uint4* sl = (const uint4*)LO;
  #pragma unroll
  for (int q = 0; q < 4; ++q){
    gh[q*256 + tid] = sh[q*256 + tid];
    gl[q*256 + tid] = sl[q*256 + tid];
  }
}

// ---------------- phase B: persistent 16-WG scan, tag-in-data exchange ----------------
__global__ __launch_bounds__(256, 1) void scan_k(
    const float* __restrict__ h0, const float* __restrict__ c0,
    const float* __restrict__ h20, const float* __restrict__ c20,
    const float* __restrict__ Wp,
    const uint16_t* __restrict__ W1hh_h, const uint16_t* __restrict__ W1hh_l,
    const uint16_t* __restrict__ W1ih_h, const uint16_t* __restrict__ W1ih_l,
    const uint16_t* __restrict__ W2ih_h, const uint16_t* __restrict__ W2ih_l,
    const uint16_t* __restrict__ W2hh_h, const uint16_t* __restrict__ W2hh_l,
    const float* __restrict__ bias1, const float* __restrict__ bias2,
    const uint32_t* __restrict__ Xhi, const uint32_t* __restrict__ Xlo,
    u32x4* Ring, uint32_t* flags2,
    float* Pbuf, u64* L2buf, u64* H2buf, float* HcHist, float* upx)
{
  __shared__ uint32_t A_hi_s[4096];
  __shared__ uint32_t A_lo_s[4096];
  __shared__ uint32_t X_hi_s[4096];
  __shared__ uint32_t X_lo_s[4096];
  __shared__ float SGf[2048];
  __shared__ float PH[2560];
  __shared__ float PC[2560];

  const int j = blockIdx.x;
  const int tid = threadIdx.x;
  const int w = tid >> 6;
  const int l = tid & 63;
  const int lm = l & 15, lq = l >> 4;
  const int bE = tid >> 3, mp = tid & 7;
  const int m0 = 2*mp, m1 = m0 + 1;

  const int r = w*256 + j*16 + lm;
  s16x8 Bhh_h[8], Bhh_l[8];
  #pragma unroll
  for (int kt = 0; kt < 8; ++kt){
    size_t o = (size_t)r*256 + kt*32 + lq*8;
    Bhh_h[kt] = *(const s16x8*)(W1hh_h + o);
    Bhh_l[kt] = *(const s16x8*)(W1hh_l + o);
  }
  const float b1v = bias1[r];
  const float b2v = bias2[r];
  const float wp0 = Wp[j*16 + m0];
  const float wp1 = Wp[j*16 + m1];

  float c1a = c0[bE*256 + j*16 + m0];
  float c1b = c0[bE*256 + j*16 + m1];
  float c2a = c20[bE*256 + j*16 + m0];
  float c2b = c20[bE*256 + j*16 + m1];

  // init: H2buf parity-slot 0 (AGT) and tagged h0 publish (tag=1, slot 0)
  __hip_atomic_store(&H2buf[bE*128 + j*8 + mp],
      splitpack64(h20[bE*256 + j*16 + m0], h20[bE*256 + j*16 + m1]), __ATOMIC_RELAXED, AGT);
  {
    uint32_t lo, hi = splitpack(h0[bE*256 + j*16 + m0], h0[bE*256 + j*16 + m1], lo);
    u32x4 u; u[0] = hi; u[1] = 1u; u[2] = lo; u[3] = 1u;
    st16_uc(Ring + bE*128 + j*8 + mp, u);
  }

  // prologue: X[0] -> X_lds, xacc = x-projection for step 0
  f32x4 xacc0 = {0.f,0.f,0.f,0.f}, xacc1 = {0.f,0.f,0.f,0.f};
  {
    const uint4* gh = (const uint4*)Xhi;
    const uint4* gl = (const uint4*)Xlo;
    #pragma unroll
    for (int q = 0; q < 4; ++q){
      ((uint4*)X_hi_s)[q*256 + tid] = gh[q*256 + tid];
      ((uint4*)X_lo_s)[q*256 + tid] = gl[q*256 + tid];
    }
    __syncthreads();
    mm3g(X_hi_s, X_lo_s, W1ih_h, W1ih_l, r, lm, lq, xacc0, xacc1);
  }

  float* hh = HcHist + (size_t)j*81920;

  for (int it = 0; it < 6400; ++it){
    const int lch = it % 80;
    // A: issue X[it+1] prefetch into registers (no wait; retired by poll's vmcnt)
    const int tn = (it < 6399) ? (it + 1) : 6399;
    const uint4* gh = (const uint4*)(Xhi + (size_t)tn*4096);
    const uint4* gl = (const uint4*)(Xlo + (size_t)tn*4096);
    uint4 xr0 = gh[tid], xr1 = gh[256+tid], xr2 = gh[512+tid], xr3 = gh[768+tid];
    uint4 yr0 = gl[tid], yr1 = gl[256+tid], yr2 = gl[512+tid], yr3 = gl[768+tid];
    // B: poll+gather h[it] (single 16-load batch, one vmcnt round per attempt)
    gather_tag16(Ring + (size_t)(it & 1)*4096, (uint32_t)(it + 1), A_hi_s, A_lo_s, tid);
    __syncthreads();
    // C: gates = xacc + h @ Whh1^T
    f32x4 acc0 = xacc0, acc1 = xacc1;
    mm3(A_hi_s, A_lo_s, Bhh_h, Bhh_l, lm, lq, acc0, acc1);
    #pragma unroll
    for (int i = 0; i < 4; ++i){
      int b0 = lq*4 + i;
      SGf[w*512 + b0*16 + lm]      = acc0[i] + b1v;
      SGf[w*512 + (b0+16)*16 + lm] = acc1[i] + b1v;
    }
    __syncthreads();
    // D: elementwise LSTM update + publish (fire-and-forget) + history + partials
    {
      float gi0 = SGf[bE*16+m0],      gi1 = SGf[bE*16+m1];
      float gf0 = SGf[512+bE*16+m0],  gf1 = SGf[512+bE*16+m1];
      float gg0 = SGf[1024+bE*16+m0], gg1 = SGf[1024+bE*16+m1];
      float go0 = SGf[1536+bE*16+m0], go1 = SGf[1536+bE*16+m1];
      float cn0 = sigf(gf0)*c1a + sigf(gi0)*tanhf(gg0);
      float cn1 = sigf(gf1)*c1b + sigf(gi1)*tanhf(gg1);
      float hn0 = sigf(go0)*tanhf(cn0);
      float hn1 = sigf(go1)*tanhf(cn1);
      c1a = cn0; c1b = cn1;
      {
        uint32_t lo, hi = splitpack(hn0, hn1, lo);
        u32x4 u; u[0] = hi; u[1] = (uint32_t)(it + 2); u[2] = lo; u[3] = (uint32_t)(it + 2);
        st16_uc(Ring + (size_t)((it + 1) & 1)*4096 + bE*128 + j*8 + mp, u);
      }
      int o = (lch*32 + bE)*16;
      hh[o + m0] = hn0; hh[o + m1] = hn1;
      hh[40960 + o + m0] = cn0; hh[40960 + o + m1] = cn1;
      float ph = hn0*wp0 + hn1*wp1;
      float pc = cn0*wp0 + cn1*wp1;
      ph += __shfl_xor(ph, 1); ph += __shfl_xor(ph, 2); ph += __shfl_xor(ph, 4);
      pc += __shfl_xor(pc, 1); pc += __shfl_xor(pc, 2); pc += __shfl_xor(pc, 4);
      if (mp == 0){ PH[lch*32 + bE] = ph; PC[lch*32 + bE] = pc; }
    }
    __syncthreads();

    if (lch == 79){
      const int ci = it / 80;
      for (int x2 = tid; x2 < 2560; x2 += 256){
        __hip_atomic_store(&Pbuf[j*5152 + x2],        PH[x2], __ATOMIC_RELAXED, AGT);
        __hip_atomic_store(&Pbuf[j*5152 + 2560 + x2], PC[x2], __ATOMIC_RELAXED, AGT);
      }
      {
        float pc2 = c2a*wp0 + c2b*wp1;
        pc2 += __shfl_xor(pc2, 1); pc2 += __shfl_xor(pc2, 2); pc2 += __shfl_xor(pc2, 4);
        if (mp == 0) __hip_atomic_store(&Pbuf[j*5152 + 5120 + bE], pc2, __ATOMIC_RELAXED, AGT);
      }
      __syncthreads();
      if (tid == 0) __hip_atomic_store(&flags2[j], (uint32_t)(2*ci + 1), __ATOMIC_RELAXED, AGT);
      if (tid < 16){
        while (__hip_atomic_load(&flags2[tid], __ATOMIC_RELAXED, AGT) < (uint32_t)(2*ci + 1))
          __builtin_amdgcn_s_sleep(1);
      }
      __syncthreads();
      for (int x2 = tid; x2 < 5152; x2 += 256){
        float s = 0.f;
        #pragma unroll
        for (int k = 0; k < 16; ++k)
          s += __hip_atomic_load(&Pbuf[k*5152 + x2], __ATOMIC_RELAXED, AGT);
        if (x2 < 2560) PH[x2] = s;
        else if (x2 < 5120) PC[x2 - 2560] = s;
        else SGf[x2 - 5120] = s;
      }
      __syncthreads();
      if (tid < 32){
        int b = tid;
        float mx = -1e30f;
        for (int l2 = 0; l2 < 80; ++l2) mx = fmaxf(mx, PH[l2*32 + b]);
        float s = 0.f;
        for (int l2 = 0; l2 < 80; ++l2){ float e = __expf(PH[l2*32+b] - mx); PH[l2*32+b] = e; s += e; }
        float inv = 1.f / s;
        for (int l2 = 0; l2 < 80; ++l2) PH[l2*32+b] *= inv;
        float mc = SGf[b];
        for (int l2 = 0; l2 < 80; ++l2) mc = fmaxf(mc, PC[l2*32 + b]);
        s = 0.f;
        for (int l2 = 0; l2 < 80; ++l2){ float e = __expf(PC[l2*32+b] - mc); PC[l2*32+b] = e; s += e; }
        float e81 = __expf(SGf[b] - mc); s += e81;
        inv = 1.f / s;
        for (int l2 = 0; l2 < 80; ++l2) PC[l2*32+b] *= inv;
        SGf[32 + b] = e81 * inv;
      }
      __syncthreads();
      float cpa = 0.f, cpb = 0.f, la = 0.f, lb = 0.f;
      for (int l2 = 0; l2 < 80; ++l2){
        float whv = PH[l2*32 + bE], wcv = PC[l2*32 + bE];
        int o = (l2*32 + bE)*16;
        la  += whv * hh[o + m0];          lb  += whv * hh[o + m1];
        cpa += wcv * hh[40960 + o + m0];  cpb += wcv * hh[40960 + o + m1];
      }
      { float w81 = SGf[32 + bE]; cpa += w81 * c2a; cpb += w81 * c2b; }
      __hip_atomic_store(&L2buf[bE*128 + j*8 + mp], splitpack64(la, lb), __ATOMIC_RELAXED, AGT);
      __syncthreads();
      if (tid == 0) __hip_atomic_store(&flags2[j], (uint32_t)(2*ci + 2), __ATOMIC_RELAXED, AGT);
      if (tid < 16){
        while (__hip_atomic_load(&flags2[tid], __ATOMIC_RELAXED, AGT) < (uint32_t)(2*ci + 2))
          __builtin_amdgcn_s_sleep(1);
      }
      __syncthreads();
      gather_u64(L2buf, A_hi_s, A_lo_s, tid);
      __syncthreads();
      f32x4 ac0 = {0.f,0.f,0.f,0.f}, ac1 = {0.f,0.f,0.f,0.f};
      mm3g(A_hi_s, A_lo_s, W2ih_h, W2ih_l, r, lm, lq, ac0, ac1);
      __syncthreads();
      gather_u64(H2buf + (size_t)(ci & 1)*4096, A_hi_s, A_lo_s, tid);
      __syncthreads();
      mm3g(A_hi_s, A_lo_s, W2hh_h, W2hh_l, r, lm, lq, ac0, ac1);
      #pragma unroll
      for (int i = 0; i < 4; ++i){
        int b0 = lq*4 + i;
        SGf[w*512 + b0*16 + lm]      = ac0[i] + b2v;
        SGf[w*512 + (b0+16)*16 + lm] = ac1[i] + b2v;
      }
      __syncthreads();
      {
        float gi0 = SGf[bE*16+m0],      gi1 = SGf[bE*16+m1];
        float gf0 = SGf[512+bE*16+m0],  gf1 = SGf[512+bE*16+m1];
        float gg0 = SGf[1024+bE*16+m0], gg1 = SGf[1024+bE*16+m1];
        float go0 = SGf[1536+bE*16+m0], go1 = SGf[1536+bE*16+m1];
        float c2n0 = sigf(gf0)*cpa + sigf(gi0)*tanhf(gg0);
        float c2n1 = sigf(gf1)*cpb + sigf(gi1)*tanhf(gg1);
        float h2v0 = sigf(go0)*tanhf(c2n0);
        float h2v1 = sigf(go1)*tanhf(c2n1);
        c2a = c2n0; c2b = c2n1;
        upx[((size_t)ci*32 + bE)*256 + j*16 + m0] = h2v0;
        upx[((size_t)ci*32 + bE)*256 + j*16 + m1] = h2v1;
        __hip_atomic_store(&H2buf[(size_t)((ci + 1) & 1)*4096 + bE*128 + j*8 + mp],
                           splitpack64(h2v0, h2v1), __ATOMIC_RELAXED, AGT);
      }
      __syncthreads();
    }

    // E: X_lds write + Wih GEMM for step it+1 (off critical path, overlaps propagation)
    if (it < 6399){
      ((uint4*)X_hi_s)[tid]       = xr0;
      ((uint4*)X_hi_s)[256 + tid] = xr1;
      ((uint4*)X_hi_s)[512 + tid] = xr2;
      ((uint4*)X_hi_s)[768 + tid] = xr3;
      ((uint4*)X_lo_s)[tid]       = yr0;
      ((uint4*)X_lo_s)[256 + tid] = yr1;
      ((uint4*)X_lo_s)[512 + tid] = yr2;
      ((uint4*)X_lo_s)[768 + tid] = yr3;
      __syncthreads();
      xacc0 = (f32x4){0.f,0.f,0.f,0.f};
      xacc1 = (f32x4){0.f,0.f,0.f,0.f};
      mm3g(X_hi_s, X_lo_s, W1ih_h, W1ih_l, r, lm, lq, xacc0, xacc1);
    }
  }
}

// ---------------- phase C: encoder attention + MLP head ----------------
__global__ __launch_bounds__(256, 1) void out_k(
    const float* __restrict__ upx, const float* __restrict__ Wu,
    const float* __restrict__ bu, const float* __restrict__ We,
    const float* __restrict__ Wo1T, const float* __restrict__ bo1,
    const float* __restrict__ Wo2T, const float* __restrict__ bo2,
    float* __restrict__ out)
{
  __shared__ float sWu[128*257];
  __shared__ float sX[256];
  __shared__ float sPP[2][128];
  __shared__ float sU[128];
  __shared__ float sET[80*4];
  __shared__ float sW[80*4];
  __shared__ float sFlat[1024];
  __shared__ float sHid[512];
  const int b = blockIdx.x, tid = threadIdx.x;
  for (int i = tid; i < 32768; i += 256){ int a2 = i >> 8, k2 = i & 255; sWu[a2*257 + k2] = Wu[i]; }
  const int a = tid & 127, kh = tid >> 7;
  for (int l2 = 0; l2 < 80; ++l2){
    __syncthreads();
    sX[tid] = upx[((size_t)l2*32 + b)*256 + tid];
    __syncthreads();
    float acc = 0.f;
    #pragma unroll 4
    for (int k = 0; k < 128; ++k)
      acc += sWu[a*257 + kh*128 + k] * sX[kh*128 + k];
    sPP[kh][a] = acc;
    __syncthreads();
    if (tid < 128) sU[tid] = tanhf(sPP[0][tid] + sPP[1][tid] + bu[tid]);
    __syncthreads();
    if (tid < 4){
      float e = 0.f;
      for (int a2 = 0; a2 < 128; ++a2) e += We[tid*128 + a2] * sU[a2];
      sET[l2*4 + tid] = e;
    }
  }
  __syncthreads();
  if (tid < 4){
    float mx = -1e30f;
    for (int l2 = 0; l2 < 80; ++l2) mx = fmaxf(mx, sET[l2*4 + tid]);
    float s = 0.f;
    for (int l2 = 0; l2 < 80; ++l2){ float e = __expf(sET[l2*4+tid] - mx); sW[l2*4+tid] = e; s += e; }
    float inv = 1.f / s;
    for (int l2 = 0; l2 < 80; ++l2) sW[l2*4+tid] *= inv;
  }
  __syncthreads();
  float a0 = 0.f, a1 = 0.f, a2 = 0.f, a3 = 0.f;
  for (int l2 = 0; l2 < 80; ++l2){
    float xv = upx[((size_t)l2*32 + b)*256 + tid];
    a0 += sW[l2*4+0]*xv; a1 += sW[l2*4+1]*xv; a2 += sW[l2*4+2]*xv; a3 += sW[l2*4+3]*xv;
  }
  sFlat[tid] = a0; sFlat[256+tid] = a1; sFlat[512+tid] = a2; sFlat[768+tid] = a3;
  __syncthreads();
  #pragma unroll
  for (int h2 = 0; h2 < 2; ++h2){
    int n = tid + h2*256;
    float acc = bo1[n];
    for (int k = 0; k < 1024; ++k) acc += Wo1T[(size_t)k*512 + n] * sFlat[k];
    sHid[n] = fmaxf(acc, 0.f);
  }
  __syncthreads();
  {
    float acc = bo2[tid];
    for (int k = 0; k < 512; ++k) acc += Wo2T[(size_t)k*256 + tid] * sHid[k];
    out[b*256 + tid] = acc;
  }
}

// ---------------- launcher ----------------
extern "C" void kernel_launch(void* const* d_in, const int* in_sizes, int n_in,
                              void* d_out, int out_size, void* d_ws, size_t ws_size,
                              hipStream_t stream)
{
  (void)in_sizes; (void)n_in; (void)out_size;
  const float* x    = (const float*)d_in[0];
  const float* Wih1 = (const float*)d_in[1];
  const float* Whh1 = (const float*)d_in[2];
  const float* bih1 = (const float*)d_in[3];
  const float* bhh1 = (const float*)d_in[4];
  const float* Wih2 = (const float*)d_in[5];
  const float* Whh2 = (const float*)d_in[6];
  const float* bih2 = (const float*)d_in[7];
  const float* bhh2 = (const float*)d_in[8];
  const float* Wp   = (const float*)d_in[9];
  const float* Wu   = (const float*)d_in[11];
  const float* bu   = (const float*)d_in[12];
  const float* We   = (const float*)d_in[13];
  const float* Wo1  = (const float*)d_in[15];
  const float* bo1  = (const float*)d_in[16];
  const float* Wo2  = (const float*)d_in[17];
  const float* bo2  = (const float*)d_in[18];
  const float* h0   = (const float*)d_in[19];
  const float* c0   = (const float*)d_in[20];
  const float* h20  = (const float*)d_in[21];
  const float* c20  = (const float*)d_in[22];
  float* out = (float*)d_out;

  if (ws_size < 230000000ULL) return;
  uint8_t* ws = (uint8_t*)d_ws;
  uint32_t* flags2 = (uint32_t*)(ws + 512);
  uint16_t* W1ih_h = (uint16_t*)(ws + 4096);
  uint16_t* W1ih_l = (uint16_t*)(ws + 528384);
  uint16_t* W1hh_h = (uint16_t*)(ws + 1052672);
  uint16_t* W1hh_l = (uint16_t*)(ws + 1576960);
  uint16_t* W2ih_h = (uint16_t*)(ws + 2101248);
  uint16_t* W2ih_l = (uint16_t*)(ws + 2625536);
  uint16_t* W2hh_h = (uint16_t*)(ws + 3149824);
  uint16_t* W2hh_l = (uint16_t*)(ws + 3674112);
  float* bias1 = (float*)(ws + 4198400);
  float* bias2 = (float*)(ws + 4202496);
  float* Wo1T  = (float*)(ws + 4206592);
  float* Wo2T  = (float*)(ws + 6303744);
  float* upx   = (float*)(ws + 6828032);
  float* Pbuf  = (float*)(ws + 9449472);
  u64*   L2buf = (u64*)(ws + 9779200);
  u64*   H2buf = (u64*)(ws + 9811968);
  float* HcHist   = (float*)(ws + 9943040);
  u32x4* Ring  = (u32x4*)(ws + 15728640);   // 2 slots x 4096 units x 16B = 128KB
  uint32_t* Xhi = (uint32_t*)(ws + 16777216);
  uint32_t* Xlo = (uint32_t*)(ws + 121634816);

  (void)hipMemsetAsync(ws, 0, 4096, stream);               // flags2
  (void)hipMemsetAsync(ws + 15728640, 0, 131072, stream);  // Ring tags (replay-safe)
  hipLaunchKernelGGL(prep_k, dim3(2048), dim3(256), 0, stream,
      Wih1, Whh1, bih1, bhh1, Wih2, Whh2, bih2, bhh2, Wo1, Wo2,
      W1ih_h, W1ih_l, W1hh_h, W1hh_l, W2ih_h, W2ih_l, W2hh_h, W2hh_l,
      bias1, bias2, Wo1T, Wo2T);
  hipLaunchKernelGGL(xsplit_k, dim3(6400), dim3(256), 0, stream, x, Xhi, Xlo);
  hipLaunchKernelGGL(scan_k, dim3(16), dim3(256), 0, stream,
      h0, c0, h20, c20, Wp,
      W1hh_h, W1hh_l, W1ih_h, W1ih_l,
      W2ih_h, W2ih_l, W2hh_h, W2hh_l,
      bias1, bias2, Xhi, Xlo,
      Ring, flags2, Pbuf, L2buf, H2buf, HcHist, upx);
  hipLaunchKernelGGL(out_k, dim3(32), dim3(256), 0, stream,
      upx, Wu, bu, We, Wo1T, bo1, Wo2T, bo2, out);
}

// Round 10
// 44826.697 us; speedup vs baseline: 1.6796x; 1.0016x over previous
//
#include <hip/hip_runtime.h>
#include <stdint.h>

#define AGT __HIP_MEMORY_SCOPE_AGENT
typedef unsigned long long u64;

typedef float f32x4 __attribute__((ext_vector_type(4)));
typedef short s16x8 __attribute__((ext_vector_type(8)));
typedef uint32_t u32x4 __attribute__((ext_vector_type(4)));

__device__ __forceinline__ uint16_t f2bf(float f){
  union { float f; uint32_t u; } v; v.f = f;
  uint32_t r = v.u + 0x7FFFu + ((v.u >> 16) & 1u);
  return (uint16_t)(r >> 16);
}
__device__ __forceinline__ float bf2f(uint16_t u){
  union { uint32_t u; float f; } v; v.u = ((uint32_t)u) << 16; return v.f;
}
__device__ __forceinline__ uint32_t splitpack(float a, float b, uint32_t& lo){
  uint16_t ah = f2bf(a), bh = f2bf(b);
  float ar = a - bf2f(ah), br = b - bf2f(bh);
  lo = (uint32_t)f2bf(ar) | ((uint32_t)f2bf(br) << 16);
  return (uint32_t)ah | ((uint32_t)bh << 16);
}
__device__ __forceinline__ u64 splitpack64(float a, float b){
  uint32_t lo, hi = splitpack(a, b, lo);
  return (u64)hi | ((u64)lo << 32);
}
__device__ __forceinline__ float sigf(float x){ return 1.0f / (1.0f + __expf(-x)); }

__device__ __forceinline__ f32x4 MFMA16(s16x8 a, s16x8 b, f32x4 c){
  return __builtin_amdgcn_mfma_f32_16x16x32_bf16(a, b, c, 0, 0, 0);
}

__device__ __forceinline__ s16x8 ldsA(const uint32_t* AH, int b, int kbyte){
  int off = b*512 + (kbyte ^ ((b & 7) << 4));
  return *(const s16x8*)((const uint8_t*)AH + off);
}

// ---- MALL-coherent tagged-unit primitives (sc0+sc1: chip-coherent, bypass L0/L2) ----
__device__ __forceinline__ void st16_uc(u32x4* p, u32x4 v){
  asm volatile("global_store_dwordx4 %0, %1, off sc0 sc1" :: "v"(p), "v"(v) : "memory");
}
// 16 coherent 16B loads (stride 256 units), ONE self-contained wait
__device__ __forceinline__ void ld16t(const u32x4* b, int tid, u32x4* v){
  const u32x4 *p0=b+tid,         *p1=b+tid+256,   *p2=b+tid+512,   *p3=b+tid+768,
              *p4=b+tid+1024,    *p5=b+tid+1280,  *p6=b+tid+1536,  *p7=b+tid+1792,
              *p8=b+tid+2048,    *p9=b+tid+2304,  *pa=b+tid+2560,  *pb=b+tid+2816,
              *pc=b+tid+3072,    *pd=b+tid+3328,  *pe=b+tid+3584,  *pf=b+tid+3840;
  asm volatile(
    "global_load_dwordx4 %0, %16, off sc0 sc1\n\t"
    "global_load_dwordx4 %1, %17, off sc0 sc1\n\t"
    "global_load_dwordx4 %2, %18, off sc0 sc1\n\t"
    "global_load_dwordx4 %3, %19, off sc0 sc1\n\t"
    "global_load_dwordx4 %4, %20, off sc0 sc1\n\t"
    "global_load_dwordx4 %5, %21, off sc0 sc1\n\t"
    "global_load_dwordx4 %6, %22, off sc0 sc1\n\t"
    "global_load_dwordx4 %7, %23, off sc0 sc1\n\t"
    "global_load_dwordx4 %8, %24, off sc0 sc1\n\t"
    "global_load_dwordx4 %9, %25, off sc0 sc1\n\t"
    "global_load_dwordx4 %10, %26, off sc0 sc1\n\t"
    "global_load_dwordx4 %11, %27, off sc0 sc1\n\t"
    "global_load_dwordx4 %12, %28, off sc0 sc1\n\t"
    "global_load_dwordx4 %13, %29, off sc0 sc1\n\t"
    "global_load_dwordx4 %14, %30, off sc0 sc1\n\t"
    "global_load_dwordx4 %15, %31, off sc0 sc1\n\t"
    "s_waitcnt vmcnt(0)"
    : "=&v"(v[0]), "=&v"(v[1]), "=&v"(v[2]), "=&v"(v[3]),
      "=&v"(v[4]), "=&v"(v[5]), "=&v"(v[6]), "=&v"(v[7]),
      "=&v"(v[8]), "=&v"(v[9]), "=&v"(v[10]), "=&v"(v[11]),
      "=&v"(v[12]), "=&v"(v[13]), "=&v"(v[14]), "=&v"(v[15])
    : "v"(p0), "v"(p1), "v"(p2), "v"(p3), "v"(p4), "v"(p5), "v"(p6), "v"(p7),
      "v"(p8), "v"(p9), "v"(pa), "v"(pb), "v"(pc), "v"(pd), "v"(pe), "v"(pf)
    : "memory");
}

// single-batch tag-polled gather: unit {hi, tag, lo, tag}; accept when all 32 tag words match.
__device__ __forceinline__ void gather_tag16(const u32x4* ring, uint32_t tag,
                                             uint32_t* Ahi, uint32_t* Alo, int tid){
  u32x4 v[16];
  ld16t(ring, tid, v);
  while (true){
    uint32_t bad = 0;
    #pragma unroll
    for (int i = 0; i < 16; ++i) bad |= (v[i][1] ^ tag) | (v[i][3] ^ tag);
    if (!bad) break;
    __builtin_amdgcn_s_sleep(1);
    ld16t(ring, tid, v);
  }
  #pragma unroll
  for (int i = 0; i < 16; ++i){
    int q = i*256 + tid; int b = q >> 7, p = q & 127;
    int off = b*512 + ((p*4) ^ ((b & 7) << 4));
    *(uint32_t*)((uint8_t*)Ahi + off) = v[i][0];
    *(uint32_t*)((uint8_t*)Alo + off) = v[i][2];
  }
}

// gather a [4096] u64 (hi,lo packed) exchange buffer -> swizzled hi/lo LDS A-images (AGT relaxed)
__device__ __forceinline__ void gather_u64(const u64* src, uint32_t* Ahi, uint32_t* Alo, int tid){
  #pragma unroll
  for (int i = 0; i < 16; ++i){
    int q = i*256 + tid;
    u64 v = __hip_atomic_load(&src[q], __ATOMIC_RELAXED, AGT);
    int b = q >> 7, p = q & 127;
    int off = b*512 + ((p*4) ^ ((b & 7) << 4));
    *(uint32_t*)((uint8_t*)Ahi + off) = (uint32_t)v;
    *(uint32_t*)((uint8_t*)Alo + off) = (uint32_t)(v >> 32);
  }
}

__device__ __forceinline__ void mm3(const uint32_t* Ahi, const uint32_t* Alo,
                                    const s16x8* Bh, const s16x8* Bl,
                                    int lm, int lq, f32x4& a0, f32x4& a1){
  #pragma unroll
  for (int kt = 0; kt < 8; ++kt){
    int kb = kt*64 + lq*16;
    s16x8 h0v = ldsA(Ahi, lm, kb), h1v = ldsA(Ahi, 16 + lm, kb);
    s16x8 l0v = ldsA(Alo, lm, kb), l1v = ldsA(Alo, 16 + lm, kb);
    a0 = MFMA16(h0v, Bh[kt], a0);  a1 = MFMA16(h1v, Bh[kt], a1);
    a0 = MFMA16(h0v, Bl[kt], a0);  a1 = MFMA16(h1v, Bl[kt], a1);
    a0 = MFMA16(l0v, Bh[kt], a0);  a1 = MFMA16(l1v, Bh[kt], a1);
  }
}

__device__ __forceinline__ void mm3g(const uint32_t* Ahi, const uint32_t* Alo,
                                     const uint16_t* Wh, const uint16_t* Wl,
                                     int r, int lm, int lq, f32x4& a0, f32x4& a1){
  #pragma unroll
  for (int kt = 0; kt < 8; ++kt){
    size_t o = (size_t)r*256 + kt*32 + lq*8;
    s16x8 bh = *(const s16x8*)(Wh + o);
    s16x8 bl = *(const s16x8*)(Wl + o);
    int kb = kt*64 + lq*16;
    s16x8 h0v = ldsA(Ahi, lm, kb), h1v = ldsA(Ahi, 16 + lm, kb);
    s16x8 l0v = ldsA(Alo, lm, kb), l1v = ldsA(Alo, 16 + lm, kb);
    a0 = MFMA16(h0v, bh, a0);  a1 = MFMA16(h1v, bh, a1);
    a0 = MFMA16(h0v, bl, a0);  a1 = MFMA16(h1v, bl, a1);
    a0 = MFMA16(l0v, bh, a0);  a1 = MFMA16(l1v, bh, a1);
  }
}

// ---------------- prep ----------------
__global__ __launch_bounds__(256) void prep_k(
    const float* __restrict__ Wih1, const float* __restrict__ Whh1,
    const float* __restrict__ bih1, const float* __restrict__ bhh1,
    const float* __restrict__ Wih2, const float* __restrict__ Whh2,
    const float* __restrict__ bih2, const float* __restrict__ bhh2,
    const float* __restrict__ Wo1, const float* __restrict__ Wo2,
    uint16_t* __restrict__ W1ih_h, uint16_t* __restrict__ W1ih_l,
    uint16_t* __restrict__ W1hh_h, uint16_t* __restrict__ W1hh_l,
    uint16_t* __restrict__ W2ih_h, uint16_t* __restrict__ W2ih_l,
    uint16_t* __restrict__ W2hh_h, uint16_t* __restrict__ W2hh_l,
    float* __restrict__ bias1, float* __restrict__ bias2,
    float* __restrict__ Wo1T, float* __restrict__ Wo2T)
{
  int i = blockIdx.x * 256 + threadIdx.x;
  if (i < 262144){
    float w; uint16_t h;
    w = Wih1[i]; h = f2bf(w); W1ih_h[i] = h; W1ih_l[i] = f2bf(w - bf2f(h));
    w = Whh1[i]; h = f2bf(w); W1hh_h[i] = h; W1hh_l[i] = f2bf(w - bf2f(h));
    w = Wih2[i]; h = f2bf(w); W2ih_h[i] = h; W2ih_l[i] = f2bf(w - bf2f(h));
    w = Whh2[i]; h = f2bf(w); W2hh_h[i] = h; W2hh_l[i] = f2bf(w - bf2f(h));
  }
  if (i < 1024){ bias1[i] = bih1[i] + bhh1[i]; bias2[i] = bih2[i] + bhh2[i]; }
  if (i < 524288){ Wo1T[i] = Wo1[(size_t)(i & 511)*1024 + (i >> 9)]; }
  if (i < 131072){ Wo2T[i] = Wo2[(size_t)(i & 255)*512 + (i >> 8)]; }
}

// ---------------- xsplit (fallback path): x -> per-t swizzled hi/lo planes ----------------
__global__ __launch_bounds__(256, 1) void xsplit_k(
    const float* __restrict__ x, uint32_t* __restrict__ Xhi, uint32_t* __restrict__ Xlo)
{
  __shared__ uint32_t HI[4096];
  __shared__ uint32_t LO[4096];
  const int t = blockIdx.x, tid = threadIdx.x;
  const int b = tid >> 3, seg = tid & 7;
  const float4* xr = (const float4*)(x + ((size_t)b*6400 + t)*256 + seg*32);
  #pragma unroll
  for (int ii = 0; ii < 8; ++ii){
    float4 v = xr[ii];
    int p0 = seg*16 + ii*2;
    uint32_t lo0, lo1;
    uint32_t hi0 = splitpack(v.x, v.y, lo0);
    uint32_t hi1 = splitpack(v.z, v.w, lo1);
    int o0 = (b*512 + (((p0  )*4) ^ ((b&7)<<4))) >> 2;
    int o1 = (b*512 + (((p0+1)*4) ^ ((b&7)<<4))) >> 2;
    HI[o0] = hi0; LO[o0] = lo0;
    HI[o1] = hi1; LO[o1] = lo1;
  }
  __syncthreads();
  uint4* gh = (uint4*)(Xhi + (size_t)t*4096);
  uint4* gl = (uint4*)(Xlo + (size_t)t*4096);
  const uint4* sh = (const uint4*)HI;
  const uint4* sl = (const uint4*)LO;
  #pragma unroll
  for (int q = 0; q < 4; ++q){
    gh[q*256 + tid] = sh[q*256 + tid];
    gl[q*256 + tid] = sl[q*256 + tid];
  }
}

// ---------------- gx (fast path): Gxf[t][j][tid*8..+7] = fp32(x_t @ W1ih^T + bias1) ----------------
// Same thread mapping as scan_k<true>: thread tid's 8 floats are exactly what scan thread tid needs.
__global__ __launch_bounds__(256, 1) void gx_k(
    const float* __restrict__ x,
    const uint16_t* __restrict__ W1ih_h, const uint16_t* __restrict__ W1ih_l,
    const float* __restrict__ bias1, float* __restrict__ Gxf)
{
  __shared__ uint32_t Xh[4096];
  __shared__ uint32_t Xl[4096];
  const int t = blockIdx.x, tid = threadIdx.x;
  const int w = tid >> 6, l = tid & 63, lm = l & 15, lq = l >> 4;
  {
    int b = tid >> 3, seg = tid & 7;
    const float4* xr = (const float4*)(x + ((size_t)b*6400 + t)*256 + seg*32);
    #pragma unroll
    for (int ii = 0; ii < 8; ++ii){
      float4 v = xr[ii];
      int p0 = seg*16 + ii*2;
      uint32_t lo0, lo1;
      uint32_t hi0 = splitpack(v.x, v.y, lo0);
      uint32_t hi1 = splitpack(v.z, v.w, lo1);
      int o0 = (b*512 + (((p0  )*4) ^ ((b&7)<<4))) >> 2;
      int o1 = (b*512 + (((p0+1)*4) ^ ((b&7)<<4))) >> 2;
      Xh[o0] = hi0; Xl[o0] = lo0;
      Xh[o1] = hi1; Xl[o1] = lo1;
    }
  }
  __syncthreads();
  for (int j = 0; j < 16; ++j){
    const int r = w*256 + j*16 + lm;
    f32x4 a0 = {0.f,0.f,0.f,0.f}, a1 = {0.f,0.f,0.f,0.f};
    mm3g(Xh, Xl, W1ih_h, W1ih_l, r, lm, lq, a0, a1);
    float bv = bias1[r];
    float4 o0 = {a0[0]+bv, a0[1]+bv, a0[2]+bv, a0[3]+bv};
    float4 o1 = {a1[0]+bv, a1[1]+bv, a1[2]+bv, a1[3]+bv};
    float4* dst = (float4*)(Gxf + ((size_t)t*16 + j)*2048 + (size_t)tid*8);
    dst[0] = o0; dst[1] = o1;
  }
}

// ---------------- phase B: persistent 16-WG scan, tag-in-data exchange ----------------
// USEGX=true: gate x-projection read from precomputed fp32 Gxf (8KB/WG/step).
// USEGX=false: R8-proven in-loop X projection (X prefetch + Wih GEMM per step).
template<bool USEGX>
__global__ __launch_bounds__(256, 1) void scan_k(
    const float* __restrict__ h0, const float* __restrict__ c0,
    const float* __restrict__ h20, const float* __restrict__ c20,
    const float* __restrict__ Wp,
    const uint16_t* __restrict__ W1hh_h, const uint16_t* __restrict__ W1hh_l,
    const uint16_t* __restrict__ W1ih_h, const uint16_t* __restrict__ W1ih_l,
    const uint16_t* __restrict__ W2ih_h, const uint16_t* __restrict__ W2ih_l,
    const uint16_t* __restrict__ W2hh_h, const uint16_t* __restrict__ W2hh_l,
    const float* __restrict__ bias1, const float* __restrict__ bias2,
    const uint32_t* __restrict__ Xhi, const uint32_t* __restrict__ Xlo,
    const float* __restrict__ Gxf,
    u32x4* Ring, uint32_t* flags2,
    float* Pbuf, u64* L2buf, u64* H2buf, float* HcHist, float* upx)
{
  __shared__ uint32_t A_hi_s[4096];
  __shared__ uint32_t A_lo_s[4096];
  __shared__ uint32_t X_hi_s[4096];
  __shared__ uint32_t X_lo_s[4096];
  __shared__ float SGf[2048];
  __shared__ float PH[2560];
  __shared__ float PC[2560];

  const int j = blockIdx.x;
  const int tid = threadIdx.x;
  const int w = tid >> 6;
  const int l = tid & 63;
  const int lm = l & 15, lq = l >> 4;
  const int bE = tid >> 3, mp = tid & 7;
  const int m0 = 2*mp, m1 = m0 + 1;

  const int r = w*256 + j*16 + lm;
  s16x8 Bhh_h[8], Bhh_l[8];
  #pragma unroll
  for (int kt = 0; kt < 8; ++kt){
    size_t o = (size_t)r*256 + kt*32 + lq*8;
    Bhh_h[kt] = *(const s16x8*)(W1hh_h + o);
    Bhh_l[kt] = *(const s16x8*)(W1hh_l + o);
  }
  const float b1v = USEGX ? 0.f : bias1[r];
  const float b2v = bias2[r];
  const float wp0 = Wp[j*16 + m0];
  const float wp1 = Wp[j*16 + m1];

  float c1a = c0[bE*256 + j*16 + m0];
  float c1b = c0[bE*256 + j*16 + m1];
  float c2a = c20[bE*256 + j*16 + m0];
  float c2b = c20[bE*256 + j*16 + m1];

  // init: H2buf parity-slot 0 (AGT) and tagged h0 publish (tag=1, slot 0)
  __hip_atomic_store(&H2buf[bE*128 + j*8 + mp],
      splitpack64(h20[bE*256 + j*16 + m0], h20[bE*256 + j*16 + m1]), __ATOMIC_RELAXED, AGT);
  {
    uint32_t lo, hi = splitpack(h0[bE*256 + j*16 + m0], h0[bE*256 + j*16 + m1], lo);
    u32x4 u; u[0] = hi; u[1] = 1u; u[2] = lo; u[3] = 1u;
    st16_uc(Ring + bE*128 + j*8 + mp, u);
  }

  // prologue (fallback only): X[0] -> X_lds, xacc = x-projection for step 0
  f32x4 xacc0 = {0.f,0.f,0.f,0.f}, xacc1 = {0.f,0.f,0.f,0.f};
  if constexpr (!USEGX){
    const uint4* gh = (const uint4*)Xhi;
    const uint4* gl = (const uint4*)Xlo;
    #pragma unroll
    for (int q = 0; q < 4; ++q){
      ((uint4*)X_hi_s)[q*256 + tid] = gh[q*256 + tid];
      ((uint4*)X_lo_s)[q*256 + tid] = gl[q*256 + tid];
    }
    __syncthreads();
    mm3g(X_hi_s, X_lo_s, W1ih_h, W1ih_l, r, lm, lq, xacc0, xacc1);
  }

  float* hh = HcHist + (size_t)j*81920;

  for (int it = 0; it < 6400; ++it){
    const int lch = it % 80;
    // A: prefetch this step's x-projection inputs (retired by poll's vmcnt)
    float4 gxa, gxb;
    uint4 xr0, xr1, xr2, xr3, yr0, yr1, yr2, yr3;
    if constexpr (USEGX){
      const float4* gp = (const float4*)(Gxf + ((size_t)it*16 + j)*2048 + (size_t)tid*8);
      gxa = gp[0]; gxb = gp[1];
    } else {
      const int tn = (it < 6399) ? (it + 1) : 6399;
      const uint4* gh = (const uint4*)(Xhi + (size_t)tn*4096);
      const uint4* gl = (const uint4*)(Xlo + (size_t)tn*4096);
      xr0 = gh[tid]; xr1 = gh[256+tid]; xr2 = gh[512+tid]; xr3 = gh[768+tid];
      yr0 = gl[tid]; yr1 = gl[256+tid]; yr2 = gl[512+tid]; yr3 = gl[768+tid];
    }
    // B: poll+gather h[it] (single 16-load batch, one vmcnt round per attempt)
    gather_tag16(Ring + (size_t)(it & 1)*4096, (uint32_t)(it + 1), A_hi_s, A_lo_s, tid);
    __syncthreads();
    // C: gates = x-part + h @ Whh1^T
    f32x4 acc0, acc1;
    if constexpr (USEGX){
      acc0 = (f32x4){0.f,0.f,0.f,0.f}; acc1 = (f32x4){0.f,0.f,0.f,0.f};
    } else {
      acc0 = xacc0; acc1 = xacc1;
    }
    mm3(A_hi_s, A_lo_s, Bhh_h, Bhh_l, lm, lq, acc0, acc1);
    if constexpr (USEGX){
      SGf[w*512 + (lq*4+0)*16 + lm] = acc0[0] + gxa.x;
      SGf[w*512 + (lq*4+1)*16 + lm] = acc0[1] + gxa.y;
      SGf[w*512 + (lq*4+2)*16 + lm] = acc0[2] + gxa.z;
      SGf[w*512 + (lq*4+3)*16 + lm] = acc0[3] + gxa.w;
      SGf[w*512 + (16+lq*4+0)*16 + lm] = acc1[0] + gxb.x;
      SGf[w*512 + (16+lq*4+1)*16 + lm] = acc1[1] + gxb.y;
      SGf[w*512 + (16+lq*4+2)*16 + lm] = acc1[2] + gxb.z;
      SGf[w*512 + (16+lq*4+3)*16 + lm] = acc1[3] + gxb.w;
    } else {
      #pragma unroll
      for (int i = 0; i < 4; ++i){
        int b0 = lq*4 + i;
        SGf[w*512 + b0*16 + lm]      = acc0[i] + b1v;
        SGf[w*512 + (b0+16)*16 + lm] = acc1[i] + b1v;
      }
    }
    __syncthreads();
    // D: elementwise LSTM update + publish (fire-and-forget) + history + partials
    {
      float gi0 = SGf[bE*16+m0],      gi1 = SGf[bE*16+m1];
      float gf0 = SGf[512+bE*16+m0],  gf1 = SGf[512+bE*16+m1];
      float gg0 = SGf[1024+bE*16+m0], gg1 = SGf[1024+bE*16+m1];
      float go0 = SGf[1536+bE*16+m0], go1 = SGf[1536+bE*16+m1];
      float cn0 = sigf(gf0)*c1a + sigf(gi0)*tanhf(gg0);
      float cn1 = sigf(gf1)*c1b + sigf(gi1)*tanhf(gg1);
      float hn0 = sigf(go0)*tanhf(cn0);
      float hn1 = sigf(go1)*tanhf(cn1);
      c1a = cn0; c1b = cn1;
      {
        uint32_t lo, hi = splitpack(hn0, hn1, lo);
        u32x4 u; u[0] = hi; u[1] = (uint32_t)(it + 2); u[2] = lo; u[3] = (uint32_t)(it + 2);
        st16_uc(Ring + (size_t)((it + 1) & 1)*4096 + bE*128 + j*8 + mp, u);
      }
      int o = (lch*32 + bE)*16;
      hh[o + m0] = hn0; hh[o + m1] = hn1;
      hh[40960 + o + m0] = cn0; hh[40960 + o + m1] = cn1;
      float ph = hn0*wp0 + hn1*wp1;
      float pc = cn0*wp0 + cn1*wp1;
      ph += __shfl_xor(ph, 1); ph += __shfl_xor(ph, 2); ph += __shfl_xor(ph, 4);
      pc += __shfl_xor(pc, 1); pc += __shfl_xor(pc, 2); pc += __shfl_xor(pc, 4);
      if (mp == 0){ PH[lch*32 + bE] = ph; PC[lch*32 + bE] = pc; }
    }
    __syncthreads();

    if (lch == 79){
      const int ci = it / 80;
      for (int x2 = tid; x2 < 2560; x2 += 256){
        __hip_atomic_store(&Pbuf[j*5152 + x2],        PH[x2], __ATOMIC_RELAXED, AGT);
        __hip_atomic_store(&Pbuf[j*5152 + 2560 + x2], PC[x2], __ATOMIC_RELAXED, AGT);
      }
      {
        float pc2 = c2a*wp0 + c2b*wp1;
        pc2 += __shfl_xor(pc2, 1); pc2 += __shfl_xor(pc2, 2); pc2 += __shfl_xor(pc2, 4);
        if (mp == 0) __hip_atomic_store(&Pbuf[j*5152 + 5120 + bE], pc2, __ATOMIC_RELAXED, AGT);
      }
      __syncthreads();
      if (tid == 0) __hip_atomic_store(&flags2[j], (uint32_t)(2*ci + 1), __ATOMIC_RELAXED, AGT);
      if (tid < 16){
        while (__hip_atomic_load(&flags2[tid], __ATOMIC_RELAXED, AGT) < (uint32_t)(2*ci + 1))
          __builtin_amdgcn_s_sleep(1);
      }
      __syncthreads();
      for (int x2 = tid; x2 < 5152; x2 += 256){
        float s = 0.f;
        #pragma unroll
        for (int k = 0; k < 16; ++k)
          s += __hip_atomic_load(&Pbuf[k*5152 + x2], __ATOMIC_RELAXED, AGT);
        if (x2 < 2560) PH[x2] = s;
        else if (x2 < 5120) PC[x2 - 2560] = s;
        else SGf[x2 - 5120] = s;
      }
      __syncthreads();
      if (tid < 32){
        int b = tid;
        float mx = -1e30f;
        for (int l2 = 0; l2 < 80; ++l2) mx = fmaxf(mx, PH[l2*32 + b]);
        float s = 0.f;
        for (int l2 = 0; l2 < 80; ++l2){ float e = __expf(PH[l2*32+b] - mx); PH[l2*32+b] = e; s += e; }
        float inv = 1.f / s;
        for (int l2 = 0; l2 < 80; ++l2) PH[l2*32+b] *= inv;
        float mc = SGf[b];
        for (int l2 = 0; l2 < 80; ++l2) mc = fmaxf(mc, PC[l2*32 + b]);
        s = 0.f;
        for (int l2 = 0; l2 < 80; ++l2){ float e = __expf(PC[l2*32+b] - mc); PC[l2*32+b] = e; s += e; }
        float e81 = __expf(SGf[b] - mc); s += e81;
        inv = 1.f / s;
        for (int l2 = 0; l2 < 80; ++l2) PC[l2*32+b] *= inv;
        SGf[32 + b] = e81 * inv;
      }
      __syncthreads();
      float cpa = 0.f, cpb = 0.f, la = 0.f, lb = 0.f;
      for (int l2 = 0; l2 < 80; ++l2){
        float whv = PH[l2*32 + bE], wcv = PC[l2*32 + bE];
        int o = (l2*32 + bE)*16;
        la  += whv * hh[o + m0];          lb  += whv * hh[o + m1];
        cpa += wcv * hh[40960 + o + m0];  cpb += wcv * hh[40960 + o + m1];
      }
      { float w81 = SGf[32 + bE]; cpa += w81 * c2a; cpb += w81 * c2b; }
      __hip_atomic_store(&L2buf[bE*128 + j*8 + mp], splitpack64(la, lb), __ATOMIC_RELAXED, AGT);
      __syncthreads();
      if (tid == 0) __hip_atomic_store(&flags2[j], (uint32_t)(2*ci + 2), __ATOMIC_RELAXED, AGT);
      if (tid < 16){
        while (__hip_atomic_load(&flags2[tid], __ATOMIC_RELAXED, AGT) < (uint32_t)(2*ci + 2))
          __builtin_amdgcn_s_sleep(1);
      }
      __syncthreads();
      gather_u64(L2buf, A_hi_s, A_lo_s, tid);
      __syncthreads();
      f32x4 ac0 = {0.f,0.f,0.f,0.f}, ac1 = {0.f,0.f,0.f,0.f};
      mm3g(A_hi_s, A_lo_s, W2ih_h, W2ih_l, r, lm, lq, ac0, ac1);
      __syncthreads();
      gather_u64(H2buf + (size_t)(ci & 1)*4096, A_hi_s, A_lo_s, tid);
      __syncthreads();
      mm3g(A_hi_s, A_lo_s, W2hh_h, W2hh_l, r, lm, lq, ac0, ac1);
      #pragma unroll
      for (int i = 0; i < 4; ++i){
        int b0 = lq*4 + i;
        SGf[w*512 + b0*16 + lm]      = ac0[i] + b2v;
        SGf[w*512 + (b0+16)*16 + lm] = ac1[i] + b2v;
      }
      __syncthreads();
      {
        float gi0 = SGf[bE*16+m0],      gi1 = SGf[bE*16+m1];
        float gf0 = SGf[512+bE*16+m0],  gf1 = SGf[512+bE*16+m1];
        float gg0 = SGf[1024+bE*16+m0], gg1 = SGf[1024+bE*16+m1];
        float go0 = SGf[1536+bE*16+m0], go1 = SGf[1536+bE*16+m1];
        float c2n0 = sigf(gf0)*cpa + sigf(gi0)*tanhf(gg0);
        float c2n1 = sigf(gf1)*cpb + sigf(gi1)*tanhf(gg1);
        float h2v0 = sigf(go0)*tanhf(c2n0);
        float h2v1 = sigf(go1)*tanhf(c2n1);
        c2a = c2n0; c2b = c2n1;
        upx[((size_t)ci*32 + bE)*256 + j*16 + m0] = h2v0;
        upx[((size_t)ci*32 + bE)*256 + j*16 + m1] = h2v1;
        __hip_atomic_store(&H2buf[(size_t)((ci + 1) & 1)*4096 + bE*128 + j*8 + mp],
                           splitpack64(h2v0, h2v1), __ATOMIC_RELAXED, AGT);
      }
      __syncthreads();
    }

    // E (fallback only): X_lds write + Wih GEMM for step it+1
    if constexpr (!USEGX){
      if (it < 6399){
        ((uint4*)X_hi_s)[tid]       = xr0;
        ((uint4*)X_hi_s)[256 + tid] = xr1;
        ((uint4*)X_hi_s)[512 + tid] = xr2;
        ((uint4*)X_hi_s)[768 + tid] = xr3;
        ((uint4*)X_lo_s)[tid]       = yr0;
        ((uint4*)X_lo_s)[256 + tid] = yr1;
        ((uint4*)X_lo_s)[512 + tid] = yr2;
        ((uint4*)X_lo_s)[768 + tid] = yr3;
        __syncthreads();
        xacc0 = (f32x4){0.f,0.f,0.f,0.f};
        xacc1 = (f32x4){0.f,0.f,0.f,0.f};
        mm3g(X_hi_s, X_lo_s, W1ih_h, W1ih_l, r, lm, lq, xacc0, xacc1);
      }
    }
  }
}

// ---------------- phase C: encoder attention + MLP head ----------------
__global__ __launch_bounds__(256, 1) void out_k(
    const float* __restrict__ upx, const float* __restrict__ Wu,
    const float* __restrict__ bu, const float* __restrict__ We,
    const float* __restrict__ Wo1T, const float* __restrict__ bo1,
    const float* __restrict__ Wo2T, const float* __restrict__ bo2,
    float* __restrict__ out)
{
  __shared__ float sWu[128*257];
  __shared__ float sX[256];
  __shared__ float sPP[2][128];
  __shared__ float sU[128];
  __shared__ float sET[80*4];
  __shared__ float sW[80*4];
  __shared__ float sFlat[1024];
  __shared__ float sHid[512];
  const int b = blockIdx.x, tid = threadIdx.x;
  for (int i = tid; i < 32768; i += 256){ int a2 = i >> 8, k2 = i & 255; sWu[a2*257 + k2] = Wu[i]; }
  const int a = tid & 127, kh = tid >> 7;
  for (int l2 = 0; l2 < 80; ++l2){
    __syncthreads();
    sX[tid] = upx[((size_t)l2*32 + b)*256 + tid];
    __syncthreads();
    float acc = 0.f;
    #pragma unroll 4
    for (int k = 0; k < 128; ++k)
      acc += sWu[a*257 + kh*128 + k] * sX[kh*128 + k];
    sPP[kh][a] = acc;
    __syncthreads();
    if (tid < 128) sU[tid] = tanhf(sPP[0][tid] + sPP[1][tid] + bu[tid]);
    __syncthreads();
    if (tid < 4){
      float e = 0.f;
      for (int a2 = 0; a2 < 128; ++a2) e += We[tid*128 + a2] * sU[a2];
      sET[l2*4 + tid] = e;
    }
  }
  __syncthreads();
  if (tid < 4){
    float mx = -1e30f;
    for (int l2 = 0; l2 < 80; ++l2) mx = fmaxf(mx, sET[l2*4 + tid]);
    float s = 0.f;
    for (int l2 = 0; l2 < 80; ++l2){ float e = __expf(sET[l2*4+tid] - mx); sW[l2*4+tid] = e; s += e; }
    float inv = 1.f / s;
    for (int l2 = 0; l2 < 80; ++l2) sW[l2*4+tid] *= inv;
  }
  __syncthreads();
  float a0 = 0.f, a1 = 0.f, a2 = 0.f, a3 = 0.f;
  for (int l2 = 0; l2 < 80; ++l2){
    float xv = upx[((size_t)l2*32 + b)*256 + tid];
    a0 += sW[l2*4+0]*xv; a1 += sW[l2*4+1]*xv; a2 += sW[l2*4+2]*xv; a3 += sW[l2*4+3]*xv;
  }
  sFlat[tid] = a0; sFlat[256+tid] = a1; sFlat[512+tid] = a2; sFlat[768+tid] = a3;
  __syncthreads();
  #pragma unroll
  for (int h2 = 0; h2 < 2; ++h2){
    int n = tid + h2*256;
    float acc = bo1[n];
    for (int k = 0; k < 1024; ++k) acc += Wo1T[(size_t)k*512 + n] * sFlat[k];
    sHid[n] = fmaxf(acc, 0.f);
  }
  __syncthreads();
  {
    float acc = bo2[tid];
    for (int k = 0; k < 512; ++k) acc += Wo2T[(size_t)k*256 + tid] * sHid[k];
    out[b*256 + tid] = acc;
  }
}

// ---------------- launcher ----------------
extern "C" void kernel_launch(void* const* d_in, const int* in_sizes, int n_in,
                              void* d_out, int out_size, void* d_ws, size_t ws_size,
                              hipStream_t stream)
{
  (void)in_sizes; (void)n_in; (void)out_size;
  const float* x    = (const float*)d_in[0];
  const float* Wih1 = (const float*)d_in[1];
  const float* Whh1 = (const float*)d_in[2];
  const float* bih1 = (const float*)d_in[3];
  const float* bhh1 = (const float*)d_in[4];
  const float* Wih2 = (const float*)d_in[5];
  const float* Whh2 = (const float*)d_in[6];
  const float* bih2 = (const float*)d_in[7];
  const float* bhh2 = (const float*)d_in[8];
  const float* Wp   = (const float*)d_in[9];
  const float* Wu   = (const float*)d_in[11];
  const float* bu   = (const float*)d_in[12];
  const float* We   = (const float*)d_in[13];
  const float* Wo1  = (const float*)d_in[15];
  const float* bo1  = (const float*)d_in[16];
  const float* Wo2  = (const float*)d_in[17];
  const float* bo2  = (const float*)d_in[18];
  const float* h0   = (const float*)d_in[19];
  const float* c0   = (const float*)d_in[20];
  const float* h20  = (const float*)d_in[21];
  const float* c20  = (const float*)d_in[22];
  float* out = (float*)d_out;

  if (ws_size < 230000000ULL) return;
  uint8_t* ws = (uint8_t*)d_ws;
  uint32_t* flags2 = (uint32_t*)(ws + 512);
  uint16_t* W1ih_h = (uint16_t*)(ws + 4096);
  uint16_t* W1ih_l = (uint16_t*)(ws + 528384);
  uint16_t* W1hh_h = (uint16_t*)(ws + 1052672);
  uint16_t* W1hh_l = (uint16_t*)(ws + 1576960);
  uint16_t* W2ih_h = (uint16_t*)(ws + 2101248);
  uint16_t* W2ih_l = (uint16_t*)(ws + 2625536);
  uint16_t* W2hh_h = (uint16_t*)(ws + 3149824);
  uint16_t* W2hh_l = (uint16_t*)(ws + 3674112);
  float* bias1 = (float*)(ws + 4198400);
  float* bias2 = (float*)(ws + 4202496);
  float* Wo1T  = (float*)(ws + 4206592);
  float* Wo2T  = (float*)(ws + 6303744);
  float* upx   = (float*)(ws + 6828032);
  float* Pbuf  = (float*)(ws + 9449472);
  u64*   L2buf = (u64*)(ws + 9779200);
  u64*   H2buf = (u64*)(ws + 9811968);
  float* HcHist   = (float*)(ws + 9943040);
  u32x4* Ring  = (u32x4*)(ws + 15728640);   // 2 slots x 4096 units x 16B = 128KB
  // fast path: fp32 Gx at +16MB (839MB). fallback: Xhi/Xlo planes (2x105MB).
  float*    Gxf = (float*)(ws + 16777216);
  uint32_t* Xhi = (uint32_t*)(ws + 16777216);
  uint32_t* Xlo = (uint32_t*)(ws + 121634816);
  const bool useGx = (ws_size >= 856000000ULL);

  (void)hipMemsetAsync(ws, 0, 4096, stream);               // flags2
  (void)hipMemsetAsync(ws + 15728640, 0, 131072, stream);  // Ring tags (replay-safe)
  hipLaunchKernelGGL(prep_k, dim3(2048), dim3(256), 0, stream,
      Wih1, Whh1, bih1, bhh1, Wih2, Whh2, bih2, bhh2, Wo1, Wo2,
      W1ih_h, W1ih_l, W1hh_h, W1hh_l, W2ih_h, W2ih_l, W2hh_h, W2hh_l,
      bias1, bias2, Wo1T, Wo2T);
  if (useGx){
    gx_k<<<dim3(6400), dim3(256), 0, stream>>>(x, W1ih_h, W1ih_l, bias1, Gxf);
    scan_k<true><<<dim3(16), dim3(256), 0, stream>>>(
        h0, c0, h20, c20, Wp,
        W1hh_h, W1hh_l, W1ih_h, W1ih_l,
        W2ih_h, W2ih_l, W2hh_h, W2hh_l,
        bias1, bias2, (const uint32_t*)nullptr, (const uint32_t*)nullptr, Gxf,
        Ring, flags2, Pbuf, L2buf, H2buf, HcHist, upx);
  } else {
    xsplit_k<<<dim3(6400), dim3(256), 0, stream>>>(x, Xhi, Xlo);
    scan_k<false><<<dim3(16), dim3(256), 0, stream>>>(
        h0, c0, h20, c20, Wp,
        W1hh_h, W1hh_l, W1ih_h, W1ih_l,
        W2ih_h, W2ih_l, W2hh_h, W2hh_l,
        bias1, bias2, Xhi, Xlo, (const float*)nullptr,
        Ring, flags2, Pbuf, L2buf, H2buf, HcHist, upx);
  }
  hipLaunchKernelGGL(out_k, dim3(32), dim3(256), 0, stream,
      upx, Wu, bu, We, Wo1T, bo1, Wo2T, bo2, out);
}